// Round 9
// baseline (208.402 us; speedup 1.0000x reference)
//
#include <hip/hip_runtime.h>
#include <cstddef>

// ---------------------------------------------------------------------------
// B=2, N=2048, C=1024, H=16, Dh=64, scale = Dh//H = 4
// 4-launch ALL-FP16 pipeline; fp32->fp16 conversion fused into GEMM staging
// (manual register staging + ds_write, register-prefetch pipelined K-loop):
//   gemm_conv<0,0>: x fp32, qkv_w fp32 -> q|k|v fp16 [3][B,H,N,64]
//   sall_sum:       S_all[bh][d] = sum_n v  (for the masked-softmax fold)
//   attn_mfma:      S=QK^T fp16 MFMA, exact full-row softmax w/ masked-logit
//                   (=1e-9) fold, P fp16 -> PV MFMA vs LDS-transposed V band
//   gemm_conv<1,1>: ao fp16, proj_w fp32 + bias -> fp32 out
// ---------------------------------------------------------------------------

typedef _Float16 f16x8 __attribute__((ext_vector_type(8)));
typedef float    f32x4 __attribute__((ext_vector_type(4)));

#define MFMA16(a, b, c) __builtin_amdgcn_mfma_f32_16x16x32_f16((a), (b), (c), 0, 0, 0)

__device__ __forceinline__ ushort f2h(float f) {
    _Float16 h = (_Float16)f;
    return *(ushort*)&h;
}
__device__ __forceinline__ float h2f(ushort u) {
    _Float16 h = *(_Float16*)&u;
    return (float)h;
}
__device__ __forceinline__ uint4 pack8(const float4& a, const float4& b) {
    uint4 r;
    r.x = (unsigned)f2h(a.x) | ((unsigned)f2h(a.y) << 16);
    r.y = (unsigned)f2h(a.z) | ((unsigned)f2h(a.w) << 16);
    r.z = (unsigned)f2h(b.x) | ((unsigned)f2h(b.y) << 16);
    r.w = (unsigned)f2h(b.z) | ((unsigned)f2h(b.w) << 16);
    return r;
}

// ---------------------------------------------------------------------------
// MFMA GEMM, 128x128 tile, BK=32, 4 waves x (4x4) 16x16x32 f16 tiles.
// Inputs converted fp32->fp16 during staging (A optionally already fp16).
// K-loop is register-prefetch pipelined: next tile's global loads are issued
// right after the LDS-write barrier, in flight during the MFMA block.
// EPI=0: scatter fp16 into q|k|v [3][B,H,N,64] (out16 = qkv base)
// EPI=1: out = acc + bias, fp32 row-major
// A16=1: A is fp16 (proj path: A = attention output)
// ---------------------------------------------------------------------------
template <int EPI, int A16>
__global__ __launch_bounds__(256) void gemm_conv(
    const void* __restrict__ A_gv, const float* __restrict__ W_g,
    const float* __restrict__ bias,
    float* __restrict__ out, ushort* __restrict__ out16,
    int K, int Nout)
{
    __shared__ ushort smem[8192];
    ushort* AS = smem;          // [128][32] fp16 row-major
    ushort* WS = smem + 4096;   // [128][32] fp16 row-major

    const int tid  = threadIdx.x;
    const int wid  = tid >> 6;
    const int lane = tid & 63;
    const int quad = lane >> 4;
    const int cl   = lane & 15;
    const int m0 = blockIdx.y * 128;
    const int n0 = blockIdx.x * 128;
    const int wm = (wid & 1) * 64;
    const int wn = (wid >> 1) * 64;

    const int srow = tid >> 1;          // 0..127 (tile row this thread stages)
    const int scol = (tid & 1) * 16;    // 0 or 16 (16-col half)

    const float*  Af = (const float*)A_gv;
    const ushort* Ah = (const ushort*)A_gv;

    float4 pa[4];   // A prefetch (fp32 path)
    uint4  pa16[2]; // A prefetch (fp16 path)
    float4 pw[4];   // W prefetch (always fp32)

#define LOAD_TILES(K0)                                                        \
    do {                                                                      \
        if (A16) {                                                            \
            const ushort* ap_ = Ah + (size_t)(m0 + srow) * K + (K0) + scol;   \
            pa16[0] = ((const uint4*)ap_)[0];                                 \
            pa16[1] = ((const uint4*)ap_)[1];                                 \
        } else {                                                              \
            const float* ap_ = Af + (size_t)(m0 + srow) * K + (K0) + scol;    \
            pa[0] = ((const float4*)ap_)[0]; pa[1] = ((const float4*)ap_)[1]; \
            pa[2] = ((const float4*)ap_)[2]; pa[3] = ((const float4*)ap_)[3]; \
        }                                                                     \
        const float* wp_ = W_g + (size_t)(n0 + srow) * K + (K0) + scol;       \
        pw[0] = ((const float4*)wp_)[0]; pw[1] = ((const float4*)wp_)[1];     \
        pw[2] = ((const float4*)wp_)[2]; pw[3] = ((const float4*)wp_)[3];     \
    } while (0)

    f32x4 acc[4][4];
#pragma unroll
    for (int i = 0; i < 4; ++i)
#pragma unroll
        for (int j = 0; j < 4; ++j) acc[i][j] = (f32x4){0.f, 0.f, 0.f, 0.f};

    LOAD_TILES(0);

    for (int k0 = 0; k0 < K; k0 += 32) {
        __syncthreads();                 // previous iter's ds_reads complete
        const int di = srow * 32 + scol;
        if (A16) {
            *(uint4*)(AS + di)     = pa16[0];
            *(uint4*)(AS + di + 8) = pa16[1];
        } else {
            *(uint4*)(AS + di)     = pack8(pa[0], pa[1]);
            *(uint4*)(AS + di + 8) = pack8(pa[2], pa[3]);
        }
        *(uint4*)(WS + di)     = pack8(pw[0], pw[1]);
        *(uint4*)(WS + di + 8) = pack8(pw[2], pw[3]);
        __syncthreads();                 // writes visible

        if (k0 + 32 < K) LOAD_TILES(k0 + 32);   // in flight during MFMA

        f16x8 ah[4], wh[4];
#pragma unroll
        for (int i = 0; i < 4; ++i) {
            ah[i] = ((const f16x8*)AS)[(wm + i * 16 + cl) * 4 + quad];
            wh[i] = ((const f16x8*)WS)[(wn + i * 16 + cl) * 4 + quad];
        }
#pragma unroll
        for (int mi = 0; mi < 4; ++mi)
#pragma unroll
            for (int ni = 0; ni < 4; ++ni)
                acc[mi][ni] = MFMA16(ah[mi], wh[ni], acc[mi][ni]);
    }
#undef LOAD_TILES

    if (EPI == 1) {
        float bb[4];
#pragma unroll
        for (int ni = 0; ni < 4; ++ni) bb[ni] = bias[n0 + wn + ni * 16 + cl];
#pragma unroll
        for (int mi = 0; mi < 4; ++mi)
#pragma unroll
            for (int r = 0; r < 4; ++r) {
                const int gm = m0 + wm + mi * 16 + quad * 4 + r;
                float* rowp = out + (size_t)gm * Nout;
#pragma unroll
                for (int ni = 0; ni < 4; ++ni) {
                    const int gn = n0 + wn + ni * 16 + cl;
                    rowp[gn] = acc[mi][ni][r] + bb[ni];
                }
            }
    } else {
#pragma unroll
        for (int mi = 0; mi < 4; ++mi)
#pragma unroll
            for (int r = 0; r < 4; ++r) {
                const int gm = m0 + wm + mi * 16 + quad * 4 + r;
                const int b  = gm >> 11;
                const int nn = gm & 2047;
#pragma unroll
                for (int ni = 0; ni < 4; ++ni) {
                    const int gn = n0 + wn + ni * 16 + cl;
                    const int s  = gn >> 10;          // 0:q 1:k 2:v
                    const int h  = (gn >> 6) & 15;
                    const int dh = gn & 63;
                    out16[(size_t)s * 4194304u + (((size_t)b * 16 + h) * 2048 + nn) * 64 + dh]
                        = f2h(acc[mi][ni][r]);
                }
            }
    }
}

// S_all[bh][d] = sum_n v[bh][n][d] from fp16 v. 32 blocks x 256 thr, LDS reduce.
__global__ void sall_sum(const ushort* __restrict__ vg16, float* __restrict__ sall)
{
    __shared__ float red[4][64];
    const int bh = blockIdx.x;
    const int tid = threadIdx.x;
    const int d = tid & 63;
    const int c = tid >> 6;
    const ushort* base = vg16 + (((size_t)bh * 2048) + (size_t)c * 512) * 64 + d;
    float s = 0.f;
#pragma unroll 8
    for (int nn = 0; nn < 512; ++nn)
        s += h2f(base[(size_t)nn * 64]);
    red[c][d] = s;
    __syncthreads();
    if (tid < 64)
        sall[bh * 64 + tid] = red[0][tid] + red[1][tid] + red[2][tid] + red[3][tid];
}

// ---------------------------------------------------------------------------
// MFMA flash-band attention (fp16). Block = one (b,h) x 64 q-rows, 4 waves,
// each wave owns 16 rows. S(16x112) = Q K^T fp16 MFMA. Softmax in C-layout
// regs (butterfly over 16-lane cl group). P~ fp16 via same-wave LDS ->
// A-layout; PV vs LDS-transposed V band; + p_mask*S_all fold.
// ---------------------------------------------------------------------------
__global__ __launch_bounds__(256) void attn_mfma(
    const ushort* __restrict__ qg, const ushort* __restrict__ kg,
    const ushort* __restrict__ vg,
    const float* __restrict__ sall,
    ushort* __restrict__ outp,
    const int* __restrict__ epoch_ptr)
{
    const int N = 2048;
    const int w = (epoch_ptr[0] < 15) ? 16 : 20;

    __shared__ ushort Pl[4][16][144];   // per-wave P~ tile
    __shared__ ushort VT[64][144];      // transposed V band [dim][seq]

    const int tid  = threadIdx.x;
    const int wid  = tid >> 6;
    const int lane = tid & 63;
    const int quad = lane >> 4;
    const int cl   = lane & 15;

    const int bh = blockIdx.x >> 5;
    const int n0 = (blockIdx.x & 31) << 6;
    const int lo = max(0, n0 - w);
    const int wm = wid * 16;
    const int hi = min(N - 1, n0 + 63 + w);
    const int cnt = hi - lo + 1;        // <= 104

    // zero VT (pad cols >= cnt stay zero)
    for (int t = tid; t < 64 * 144 / 2; t += 256)
        ((unsigned*)VT)[t] = 0u;
    __syncthreads();

    // scatter V band (coalesced reads) into VT transposed
    for (int t = tid; t < 104 * 8; t += 256) {
        const int s  = t >> 3;
        const int db = (t & 7) * 8;
        if (s < cnt) {
            uint4 vv = *(const uint4*)(vg + (((size_t)bh * N) + lo + s) * 64 + db);
            VT[db + 0][s] = (ushort)(vv.x & 0xffff); VT[db + 1][s] = (ushort)(vv.x >> 16);
            VT[db + 2][s] = (ushort)(vv.y & 0xffff); VT[db + 3][s] = (ushort)(vv.y >> 16);
            VT[db + 4][s] = (ushort)(vv.z & 0xffff); VT[db + 5][s] = (ushort)(vv.z >> 16);
            VT[db + 6][s] = (ushort)(vv.w & 0xffff); VT[db + 7][s] = (ushort)(vv.w >> 16);
        }
    }
    // (no barrier yet: S/softmax below overlaps the scatter; barrier before PV)

    // Q A-frags straight from global (lane cl = row, quad = k-offset)
    const ushort* qp = qg + ((size_t)bh * N + n0 + wm + cl) * 64;
    const f16x8 aq0 = *(const f16x8*)(qp + quad * 8);
    const f16x8 aq1 = *(const f16x8*)(qp + 32 + quad * 8);

    // S tiles: 7 ni x (K=64 in 2 steps)
    f32x4 sacc[7];
#pragma unroll
    for (int ni = 0; ni < 7; ++ni) {
        int krow = lo + ni * 16 + cl;
        krow = min(krow, N - 1);                 // clamped rows masked later
        const ushort* kp = kg + ((size_t)bh * N + krow) * 64;
        const f16x8 bk0 = *(const f16x8*)(kp + quad * 8);
        const f16x8 bk1 = *(const f16x8*)(kp + 32 + quad * 8);
        f32x4 s = (f32x4){0.f, 0.f, 0.f, 0.f};
        s = MFMA16(aq0, bk0, s);
        s = MFMA16(aq1, bk1, s);
        sacc[ni] = s;
    }

    // softmax per row r (C-layout: row = quad*4+r, col = ni*16+cl)
    float pm[4];
#pragma unroll
    for (int r = 0; r < 4; ++r) {
        const int n = n0 + wm + quad * 4 + r;
        const int jlo = max(0, n - w), jhi = min(N - 1, n + w);
        const int bc = jhi - jlo + 1;
        float mx = 1e-9f;
#pragma unroll
        for (int ni = 0; ni < 7; ++ni) {
            const int j = lo + ni * 16 + cl;
            const bool val = (j >= n - w) && (j <= n + w) && (j < N);
            const float sv = 4.0f * sacc[ni][r];
            if (val) mx = fmaxf(mx, sv);
        }
        mx = fmaxf(mx, __shfl_xor(mx, 1));
        mx = fmaxf(mx, __shfl_xor(mx, 2));
        mx = fmaxf(mx, __shfl_xor(mx, 4));
        mx = fmaxf(mx, __shfl_xor(mx, 8));
        const float em = __expf(1e-9f - mx);
        float e[7];
        float sum = 0.f;
#pragma unroll
        for (int ni = 0; ni < 7; ++ni) {
            const int j = lo + ni * 16 + cl;
            const bool val = (j >= n - w) && (j <= n + w) && (j < N);
            const float ev = val ? __expf(4.0f * sacc[ni][r] - mx) : 0.f;
            e[ni] = val ? (ev - em) : 0.f;
            sum += ev;
        }
        sum += __shfl_xor(sum, 1);
        sum += __shfl_xor(sum, 2);
        sum += __shfl_xor(sum, 4);
        sum += __shfl_xor(sum, 8);
        const float inv = 1.0f / ((float)(N - bc) * em + sum);
        pm[r] = em * inv;
#pragma unroll
        for (int ni = 0; ni < 7; ++ni)
            sacc[ni][r] = e[ni] * inv;           // P~ = (e - em)/denom
    }

    // P~ -> LDS fp16 (same-wave slice) + zero the k-pad cols 112..143
#pragma unroll
    for (int ni = 0; ni < 7; ++ni)
#pragma unroll
        for (int r = 0; r < 4; ++r)
            Pl[wid][quad * 4 + r][ni * 16 + cl] = f2h(sacc[ni][r]);
    {
        const int prow = lane >> 2;
        const int pc = 112 + (lane & 3) * 8;
        *(uint4*)&Pl[wid][prow][pc] = make_uint4(0u, 0u, 0u, 0u);
    }

    __syncthreads();   // VT scatter complete (and P~ safely ordered)

    // PV: out(16 rows x 64 dims) = P~ (16x128) . Vband (128x64)
    const int b = bh >> 4, h = bh & 15;
#pragma unroll
    for (int dn = 0; dn < 4; ++dn) {
        f32x4 o = (f32x4){0.f, 0.f, 0.f, 0.f};
#pragma unroll
        for (int k0 = 0; k0 < 128; k0 += 32) {
            const f16x8 a  = *(const f16x8*)&Pl[wid][cl][k0 + quad * 8];
            const f16x8 bb = *(const f16x8*)&VT[dn * 16 + cl][k0 + quad * 8];
            o = MFMA16(a, bb, o);
        }
        const int d = dn * 16 + cl;
        const float sv = sall[bh * 64 + d];
#pragma unroll
        for (int r = 0; r < 4; ++r) {
            const int n = n0 + wm + quad * 4 + r;
            outp[((size_t)b * N + n) * 1024 + h * 64 + d] = f2h(o[r] + pm[r] * sv);
        }
    }
}

extern "C" void kernel_launch(void* const* d_in, const int* in_sizes, int n_in,
                              void* d_out, int out_size, void* d_ws, size_t ws_size,
                              hipStream_t stream)
{
    const float* x      = (const float*)d_in[0];
    const float* qkv_w  = (const float*)d_in[1];
    const float* proj_w = (const float*)d_in[2];
    const float* proj_b = (const float*)d_in[3];
    const int*   epoch  = (const int*)d_in[4];
    float* out = (float*)d_out;

    const size_t BHND = (size_t)2 * 16 * 2048 * 64;   // 4,194,304

    ushort* qkv16 = (ushort*)d_ws;            // q|k|v fp16, contiguous
    ushort* q16   = qkv16;
    ushort* k16   = qkv16 + BHND;
    ushort* v16   = qkv16 + 2 * BHND;
    float*  sall  = (float*)(qkv16 + 3 * BHND);   // 2048 floats (pad 4096)
    ushort* ao    = (ushort*)(sall + 4096);       // attn out fp16 [B,N,1024]

    // qkv: fp32 inputs, fused convert, scatter q|k|v fp16
    gemm_conv<0, 0><<<dim3(24, 32), dim3(256), 0, stream>>>(
        x, qkv_w, nullptr, nullptr, qkv16, 1024, 3072);

    sall_sum<<<dim3(32), dim3(256), 0, stream>>>(v16, sall);

    attn_mfma<<<dim3(1024), dim3(256), 0, stream>>>(
        q16, k16, v16, sall, ao, epoch);

    // proj: A fp16 (attn out), W fp32 fused convert, + bias -> fp32
    gemm_conv<1, 1><<<dim3(8, 32), dim3(256), 0, stream>>>(
        ao, proj_w, proj_b, out, nullptr, 1024, 1024);
}

// Round 10
// 177.618 us; speedup vs baseline: 1.1733x; 1.1733x over previous
//
#include <hip/hip_runtime.h>
#include <cstddef>

// ---------------------------------------------------------------------------
// B=2, N=2048, C=1024, H=16, Dh=64, scale = Dh//H = 4
// 4-launch ALL-FP16 pipeline (round-8 GEMM structure restored):
//   split_all:   x, qkv_w, proj_w -> fp16 (one launch)
//   gemm_mfma<0>: gl_lds16-staged fp16 MFMA -> q|k|v fp16 [3][B,H,N,64]
//   attn_mfma:   S=QK^T fp16 MFMA, exact full-row softmax w/ masked-logit
//                (=1e-9) fold, P fp16 -> PV MFMA vs LDS-transposed V band.
//                S_all (column sum of V) computed IN-KERNEL (fused, saves a
//                launch; 32 blocks/head redo an L2-resident 256KB sum).
//   gemm_mfma<1>: proj fp16 MFMA + bias -> fp32 out
// ---------------------------------------------------------------------------

typedef _Float16 f16x8 __attribute__((ext_vector_type(8)));
typedef float    f32x4 __attribute__((ext_vector_type(4)));

#define MFMA16(a, b, c) __builtin_amdgcn_mfma_f32_16x16x32_f16((a), (b), (c), 0, 0, 0)

__device__ __forceinline__ void gl_lds16(const void* g, void* l) {
    __builtin_amdgcn_global_load_lds(
        (const __attribute__((address_space(1))) void*)g,
        (__attribute__((address_space(3))) void*)l, 16, 0, 0);
}

__device__ __forceinline__ ushort f2h(float f) {
    _Float16 h = (_Float16)f;
    return *(ushort*)&h;
}
__device__ __forceinline__ float h2f(ushort u) {
    _Float16 h = *(_Float16*)&u;
    return (float)h;
}

// ---------------------------------------------------------------------------
// fused fp32 -> fp16 conversion for all three tensors in one launch.
// ---------------------------------------------------------------------------
__global__ void split_all(const float* __restrict__ x,
                          const float* __restrict__ qkvw,
                          const float* __restrict__ projw,
                          ushort* __restrict__ x16,
                          ushort* __restrict__ w16,
                          ushort* __restrict__ pw16)
{
    const int i = blockIdx.x * 256 + threadIdx.x;
    const float* src; ushort* dst; int j;
    if (i < 1048576)      { src = x;     dst = x16;  j = i; }
    else if (i < 1835008) { src = qkvw;  dst = w16;  j = i - 1048576; }
    else                  { src = projw; dst = pw16; j = i - 1835008; }

    float4 v = ((const float4*)src)[j];
    ((ushort4*)dst)[j] = make_ushort4(f2h(v.x), f2h(v.y), f2h(v.z), f2h(v.w));
}

// ---------------------------------------------------------------------------
// MFMA GEMM (m97 structure): 128x128 tile, BK=32, 4 waves x (4x4) 16x16x32 f16.
// EPI=0: scatter fp16 into q|k|v [3][B,H,N,64] (out16 = qkv base)
// EPI=1: out = acc + bias, fp32 row-major
// ---------------------------------------------------------------------------
template <int EPI>
__global__ __launch_bounds__(256) void gemm_mfma(
    const ushort* __restrict__ A_g, const ushort* __restrict__ W_g,
    const float* __restrict__ bias,
    float* __restrict__ out, ushort* __restrict__ out16,
    int K, int Nout)
{
    __shared__ ushort smem[8192];
    ushort* AS = smem;
    ushort* WS = smem + 4096;

    const int tid  = threadIdx.x;
    const int wid  = tid >> 6;
    const int lane = tid & 63;
    const int quad = lane >> 4;
    const int cl   = lane & 15;
    const int m0 = blockIdx.y * 128;
    const int n0 = blockIdx.x * 128;
    const int wm = (wid & 1) * 64;
    const int wn = (wid >> 1) * 64;

    const int srow = lane >> 2;
    const int scol = (lane & 3) * 8;

    const ushort* src = (wid < 2) ? A_g : W_g;
    ushort* dst = (wid < 2) ? AS : WS;
    const int r0 = (wid < 2) ? m0 : n0;
    const int c0 = (wid & 1) * 4;

    f32x4 acc[4][4];
#pragma unroll
    for (int i = 0; i < 4; ++i)
#pragma unroll
        for (int j = 0; j < 4; ++j) acc[i][j] = (f32x4){0.f, 0.f, 0.f, 0.f};

    for (int k0 = 0; k0 < K; k0 += 32) {
#pragma unroll
        for (int c = 0; c < 4; ++c) {
            const int cc = c0 + c;
            gl_lds16(src + (size_t)(r0 + cc * 16 + srow) * K + k0 + scol, dst + cc * 512);
        }
        __syncthreads();

        f16x8 ah[4], wh[4];
#pragma unroll
        for (int i = 0; i < 4; ++i) {
            ah[i] = ((const f16x8*)AS)[(wm + i * 16 + cl) * 4 + quad];
            wh[i] = ((const f16x8*)WS)[(wn + i * 16 + cl) * 4 + quad];
        }
#pragma unroll
        for (int mi = 0; mi < 4; ++mi)
#pragma unroll
            for (int ni = 0; ni < 4; ++ni)
                acc[mi][ni] = MFMA16(ah[mi], wh[ni], acc[mi][ni]);
        __syncthreads();
    }

    if (EPI == 1) {
        float bb[4];
#pragma unroll
        for (int ni = 0; ni < 4; ++ni) bb[ni] = bias[n0 + wn + ni * 16 + cl];
#pragma unroll
        for (int mi = 0; mi < 4; ++mi)
#pragma unroll
            for (int r = 0; r < 4; ++r) {
                const int gm = m0 + wm + mi * 16 + quad * 4 + r;
                float* rowp = out + (size_t)gm * Nout;
#pragma unroll
                for (int ni = 0; ni < 4; ++ni) {
                    const int gn = n0 + wn + ni * 16 + cl;
                    rowp[gn] = acc[mi][ni][r] + bb[ni];
                }
            }
    } else {
#pragma unroll
        for (int mi = 0; mi < 4; ++mi)
#pragma unroll
            for (int r = 0; r < 4; ++r) {
                const int gm = m0 + wm + mi * 16 + quad * 4 + r;
                const int b  = gm >> 11;
                const int nn = gm & 2047;
#pragma unroll
                for (int ni = 0; ni < 4; ++ni) {
                    const int gn = n0 + wn + ni * 16 + cl;
                    const int s  = gn >> 10;          // 0:q 1:k 2:v
                    const int h  = (gn >> 6) & 15;
                    const int dh = gn & 63;
                    out16[(size_t)s * 4194304u + (((size_t)b * 16 + h) * 2048 + nn) * 64 + dh]
                        = f2h(acc[mi][ni][r]);
                }
            }
    }
}

// ---------------------------------------------------------------------------
// MFMA flash-band attention (fp16) with FUSED S_all. Block = one (b,h) x 64
// q-rows, 4 waves x 16 rows. S(16x112) = Q K^T fp16 MFMA; softmax in C-layout
// regs (butterfly over 16-lane cl group); P~ fp16 via same-wave LDS ->
// A-layout; PV vs LDS-transposed V band; + p_mask*S_all fold.
// S_all[d] = sum_n V[bh][n][d] summed in-block (fp16 pair adds, fp32 reduce).
// ---------------------------------------------------------------------------
__global__ __launch_bounds__(256) void attn_mfma(
    const ushort* __restrict__ qg, const ushort* __restrict__ kg,
    const ushort* __restrict__ vg,
    ushort* __restrict__ outp,
    const int* __restrict__ epoch_ptr)
{
    const int N = 2048;
    const int w = (epoch_ptr[0] < 15) ? 16 : 20;

    __shared__ ushort Pl[4][16][144];     // per-wave P~ tile
    __shared__ ushort VT[64][144];        // transposed V band [dim][seq]
    __shared__ _Float16 SallRed[32][64];  // per-group partial column sums
    __shared__ float Sfin[64];            // final S_all

    const int tid  = threadIdx.x;
    const int wid  = tid >> 6;
    const int lane = tid & 63;
    const int quad = lane >> 4;
    const int cl   = lane & 15;

    const int bh = blockIdx.x >> 5;
    const int n0 = (blockIdx.x & 31) << 6;
    const int lo = max(0, n0 - w);
    const int wm = wid * 16;
    const int hi = min(N - 1, n0 + 63 + w);
    const int cnt = hi - lo + 1;        // <= 104

    // zero VT (pad cols >= cnt stay zero)
    for (int t = tid; t < 64 * 144 / 2; t += 256)
        ((unsigned*)VT)[t] = 0u;

    // fused S_all partials: group g = tid>>3 owns rows g, g+32, ...;
    // slice ds = tid&7 owns dims ds*8..ds*8+8. fp16 pair accumulation
    // (64 values/lane, |sum| < ~30 -- well inside fp16 range).
    {
        const int ds = tid & 7;
        const int grp = tid >> 3;
        const ushort* vp = vg + ((size_t)bh * N + grp) * 64 + ds * 8;
        f16x8 vacc = (f16x8){0, 0, 0, 0, 0, 0, 0, 0};
#pragma unroll 8
        for (int it = 0; it < 64; ++it)
            vacc = vacc + *(const f16x8*)(vp + (size_t)it * 32 * 64);
        *(f16x8*)&SallRed[grp][ds * 8] = vacc;
    }
    __syncthreads();    // VT zero + SallRed partials complete

    // wave 0 folds the 32 partials into Sfin while others stage VT
    if (tid < 64) {
        float s = 0.f;
#pragma unroll
        for (int j = 0; j < 32; ++j) s += (float)SallRed[j][tid];
        Sfin[tid] = s;
    }

    // scatter V band (coalesced reads) into VT transposed
    for (int t = tid; t < 104 * 8; t += 256) {
        const int s  = t >> 3;
        const int db = (t & 7) * 8;
        if (s < cnt) {
            uint4 vv = *(const uint4*)(vg + (((size_t)bh * N) + lo + s) * 64 + db);
            VT[db + 0][s] = (ushort)(vv.x & 0xffff); VT[db + 1][s] = (ushort)(vv.x >> 16);
            VT[db + 2][s] = (ushort)(vv.y & 0xffff); VT[db + 3][s] = (ushort)(vv.y >> 16);
            VT[db + 4][s] = (ushort)(vv.z & 0xffff); VT[db + 5][s] = (ushort)(vv.z >> 16);
            VT[db + 6][s] = (ushort)(vv.w & 0xffff); VT[db + 7][s] = (ushort)(vv.w >> 16);
        }
    }
    // (no barrier yet: S/softmax below overlaps the scatter; barrier before PV)

    // Q A-frags straight from global (lane cl = row, quad = k-offset)
    const ushort* qp = qg + ((size_t)bh * N + n0 + wm + cl) * 64;
    const f16x8 aq0 = *(const f16x8*)(qp + quad * 8);
    const f16x8 aq1 = *(const f16x8*)(qp + 32 + quad * 8);

    // S tiles: 7 ni x (K=64 in 2 steps)
    f32x4 sacc[7];
#pragma unroll
    for (int ni = 0; ni < 7; ++ni) {
        int krow = lo + ni * 16 + cl;
        krow = min(krow, N - 1);                 // clamped rows masked later
        const ushort* kp = kg + ((size_t)bh * N + krow) * 64;
        const f16x8 bk0 = *(const f16x8*)(kp + quad * 8);
        const f16x8 bk1 = *(const f16x8*)(kp + 32 + quad * 8);
        f32x4 s = (f32x4){0.f, 0.f, 0.f, 0.f};
        s = MFMA16(aq0, bk0, s);
        s = MFMA16(aq1, bk1, s);
        sacc[ni] = s;
    }

    // softmax per row r (C-layout: row = quad*4+r, col = ni*16+cl)
    float pm[4];
#pragma unroll
    for (int r = 0; r < 4; ++r) {
        const int n = n0 + wm + quad * 4 + r;
        const int jlo = max(0, n - w), jhi = min(N - 1, n + w);
        const int bc = jhi - jlo + 1;
        float mx = 1e-9f;
#pragma unroll
        for (int ni = 0; ni < 7; ++ni) {
            const int j = lo + ni * 16 + cl;
            const bool val = (j >= n - w) && (j <= n + w) && (j < N);
            const float sv = 4.0f * sacc[ni][r];
            if (val) mx = fmaxf(mx, sv);
        }
        mx = fmaxf(mx, __shfl_xor(mx, 1));
        mx = fmaxf(mx, __shfl_xor(mx, 2));
        mx = fmaxf(mx, __shfl_xor(mx, 4));
        mx = fmaxf(mx, __shfl_xor(mx, 8));
        const float em = __expf(1e-9f - mx);
        float e[7];
        float sum = 0.f;
#pragma unroll
        for (int ni = 0; ni < 7; ++ni) {
            const int j = lo + ni * 16 + cl;
            const bool val = (j >= n - w) && (j <= n + w) && (j < N);
            const float ev = val ? __expf(4.0f * sacc[ni][r] - mx) : 0.f;
            e[ni] = val ? (ev - em) : 0.f;
            sum += ev;
        }
        sum += __shfl_xor(sum, 1);
        sum += __shfl_xor(sum, 2);
        sum += __shfl_xor(sum, 4);
        sum += __shfl_xor(sum, 8);
        const float inv = 1.0f / ((float)(N - bc) * em + sum);
        pm[r] = em * inv;
#pragma unroll
        for (int ni = 0; ni < 7; ++ni)
            sacc[ni][r] = e[ni] * inv;           // P~ = (e - em)/denom
    }

    // P~ -> LDS fp16 (same-wave slice) + zero the k-pad cols 112..143
#pragma unroll
    for (int ni = 0; ni < 7; ++ni)
#pragma unroll
        for (int r = 0; r < 4; ++r)
            Pl[wid][quad * 4 + r][ni * 16 + cl] = f2h(sacc[ni][r]);
    {
        const int prow = lane >> 2;
        const int pc = 112 + (lane & 3) * 8;
        *(uint4*)&Pl[wid][prow][pc] = make_uint4(0u, 0u, 0u, 0u);
    }

    __syncthreads();   // VT scatter + Sfin complete (P~ safely ordered)

    // PV: out(16 rows x 64 dims) = P~ (16x128) . Vband (128x64)
    const int b = bh >> 4, h = bh & 15;
#pragma unroll
    for (int dn = 0; dn < 4; ++dn) {
        f32x4 o = (f32x4){0.f, 0.f, 0.f, 0.f};
#pragma unroll
        for (int k0 = 0; k0 < 128; k0 += 32) {
            const f16x8 a  = *(const f16x8*)&Pl[wid][cl][k0 + quad * 8];
            const f16x8 bb = *(const f16x8*)&VT[dn * 16 + cl][k0 + quad * 8];
            o = MFMA16(a, bb, o);
        }
        const int d = dn * 16 + cl;
        const float sv = Sfin[d];
#pragma unroll
        for (int r = 0; r < 4; ++r) {
            const int n = n0 + wm + quad * 4 + r;
            outp[((size_t)b * N + n) * 1024 + h * 64 + d] = f2h(o[r] + pm[r] * sv);
        }
    }
}

extern "C" void kernel_launch(void* const* d_in, const int* in_sizes, int n_in,
                              void* d_out, int out_size, void* d_ws, size_t ws_size,
                              hipStream_t stream)
{
    const float* x      = (const float*)d_in[0];
    const float* qkv_w  = (const float*)d_in[1];
    const float* proj_w = (const float*)d_in[2];
    const float* proj_b = (const float*)d_in[3];
    const int*   epoch  = (const int*)d_in[4];
    float* out = (float*)d_out;

    const size_t BHND = (size_t)2 * 16 * 2048 * 64;   // 4,194,304
    const size_t XN = 4194304, WN = 3145728;

    ushort* qkv16 = (ushort*)d_ws;            // q|k|v fp16, contiguous
    ushort* q16   = qkv16;
    ushort* k16   = qkv16 + BHND;
    ushort* v16   = qkv16 + 2 * BHND;
    ushort* x16   = qkv16 + 3 * BHND;
    ushort* w16   = x16 + XN;
    ushort* pw16  = w16 + WN;
    ushort* ao    = x16;   // alias: x16 dead after qkv gemm

    split_all<<<dim3(8192), dim3(256), 0, stream>>>(x, qkv_w, proj_w, x16, w16, pw16);

    // qkv: one uniform fp16 launch, scatter q|k|v
    gemm_mfma<0><<<dim3(24, 32), dim3(256), 0, stream>>>(
        x16, w16, nullptr, nullptr, qkv16, 1024, 3072);

    attn_mfma<<<dim3(1024), dim3(256), 0, stream>>>(
        q16, k16, v16, ao, epoch);

    gemm_mfma<1><<<dim3(8, 32), dim3(256), 0, stream>>>(
        ao, pw16, proj_b, out, nullptr, 1024, 1024);
}

// Round 11
// 167.869 us; speedup vs baseline: 1.2415x; 1.0581x over previous
//
#include <hip/hip_runtime.h>
#include <cstddef>

// ---------------------------------------------------------------------------
// B=2, N=2048, C=1024, H=16, Dh=64, scale = Dh//H = 4
// 4-launch ALL-FP16 pipeline:
//   split_all:    x, qkv_w, proj_w -> fp16 (one launch)
//   gemm_mfma<0>: gl_lds16-staged fp16 MFMA 128x128 -> q|k|v fp16 [3][B,H,N,64]
//   attn_mfma:    S=QK^T fp16 MFMA, exact full-row softmax w/ masked-logit
//                 (=1e-9) fold, fused S_all, P fp16 -> PV MFMA vs LDS V^T band
//   gemm_proj:    64x128 tiles (512 blocks = 2/CU so barrier drains overlap),
//                 fp16 MFMA + bias -> fp32 out
// ---------------------------------------------------------------------------

typedef _Float16 f16x8 __attribute__((ext_vector_type(8)));
typedef float    f32x4 __attribute__((ext_vector_type(4)));

#define MFMA16(a, b, c) __builtin_amdgcn_mfma_f32_16x16x32_f16((a), (b), (c), 0, 0, 0)

__device__ __forceinline__ void gl_lds16(const void* g, void* l) {
    __builtin_amdgcn_global_load_lds(
        (const __attribute__((address_space(1))) void*)g,
        (__attribute__((address_space(3))) void*)l, 16, 0, 0);
}

__device__ __forceinline__ ushort f2h(float f) {
    _Float16 h = (_Float16)f;
    return *(ushort*)&h;
}

// ---------------------------------------------------------------------------
// fused fp32 -> fp16 conversion for all three tensors in one launch.
// ---------------------------------------------------------------------------
__global__ void split_all(const float* __restrict__ x,
                          const float* __restrict__ qkvw,
                          const float* __restrict__ projw,
                          ushort* __restrict__ x16,
                          ushort* __restrict__ w16,
                          ushort* __restrict__ pw16)
{
    const int i = blockIdx.x * 256 + threadIdx.x;
    const float* src; ushort* dst; int j;
    if (i < 1048576)      { src = x;     dst = x16;  j = i; }
    else if (i < 1835008) { src = qkvw;  dst = w16;  j = i - 1048576; }
    else                  { src = projw; dst = pw16; j = i - 1835008; }

    float4 v = ((const float4*)src)[j];
    ((ushort4*)dst)[j] = make_ushort4(f2h(v.x), f2h(v.y), f2h(v.z), f2h(v.w));
}

// ---------------------------------------------------------------------------
// qkv MFMA GEMM (m97 structure): 128x128 tile, BK=32, 4 waves x (4x4) 16x16x32.
// Scatter fp16 into q|k|v [3][B,H,N,64].
// ---------------------------------------------------------------------------
__global__ __launch_bounds__(256) void gemm_mfma(
    const ushort* __restrict__ A_g, const ushort* __restrict__ W_g,
    ushort* __restrict__ out16, int K)
{
    __shared__ ushort smem[8192];
    ushort* AS = smem;
    ushort* WS = smem + 4096;

    const int tid  = threadIdx.x;
    const int wid  = tid >> 6;
    const int lane = tid & 63;
    const int quad = lane >> 4;
    const int cl   = lane & 15;
    const int m0 = blockIdx.y * 128;
    const int n0 = blockIdx.x * 128;
    const int wm = (wid & 1) * 64;
    const int wn = (wid >> 1) * 64;

    const int srow = lane >> 2;
    const int scol = (lane & 3) * 8;

    const ushort* src = (wid < 2) ? A_g : W_g;
    ushort* dst = (wid < 2) ? AS : WS;
    const int r0 = (wid < 2) ? m0 : n0;
    const int c0 = (wid & 1) * 4;

    f32x4 acc[4][4];
#pragma unroll
    for (int i = 0; i < 4; ++i)
#pragma unroll
        for (int j = 0; j < 4; ++j) acc[i][j] = (f32x4){0.f, 0.f, 0.f, 0.f};

    for (int k0 = 0; k0 < K; k0 += 32) {
#pragma unroll
        for (int c = 0; c < 4; ++c) {
            const int cc = c0 + c;
            gl_lds16(src + (size_t)(r0 + cc * 16 + srow) * K + k0 + scol, dst + cc * 512);
        }
        __syncthreads();

        f16x8 ah[4], wh[4];
#pragma unroll
        for (int i = 0; i < 4; ++i) {
            ah[i] = ((const f16x8*)AS)[(wm + i * 16 + cl) * 4 + quad];
            wh[i] = ((const f16x8*)WS)[(wn + i * 16 + cl) * 4 + quad];
        }
#pragma unroll
        for (int mi = 0; mi < 4; ++mi)
#pragma unroll
            for (int ni = 0; ni < 4; ++ni)
                acc[mi][ni] = MFMA16(ah[mi], wh[ni], acc[mi][ni]);
        __syncthreads();
    }

#pragma unroll
    for (int mi = 0; mi < 4; ++mi)
#pragma unroll
        for (int r = 0; r < 4; ++r) {
            const int gm = m0 + wm + mi * 16 + quad * 4 + r;
            const int b  = gm >> 11;
            const int nn = gm & 2047;
#pragma unroll
            for (int ni = 0; ni < 4; ++ni) {
                const int gn = n0 + wn + ni * 16 + cl;
                const int s  = gn >> 10;          // 0:q 1:k 2:v
                const int h  = (gn >> 6) & 15;
                const int dh = gn & 63;
                out16[(size_t)s * 4194304u + (((size_t)b * 16 + h) * 2048 + nn) * 64 + dh]
                    = f2h(acc[mi][ni][r]);
            }
        }
}

// ---------------------------------------------------------------------------
// Proj GEMM, 64x128 tiles -> 512 blocks (2 blocks/CU: co-resident block hides
// the K-loop barrier drain). 4 waves, each 32x64 (2x4 16x16 tiles, 8 MFMA/it).
// Balanced staging: every wave stages 3 of the 12 1KB chunks (A:4, W:8).
// ---------------------------------------------------------------------------
__global__ __launch_bounds__(256) void gemm_proj(
    const ushort* __restrict__ A_g, const ushort* __restrict__ W_g,
    const float* __restrict__ bias, float* __restrict__ out)
{
    const int K = 1024, Nout = 1024;
    __shared__ ushort smem[6144];
    ushort* AS = smem;          // [64][32] fp16
    ushort* WS = smem + 2048;   // [128][32] fp16

    const int tid  = threadIdx.x;
    const int wid  = tid >> 6;
    const int lane = tid & 63;
    const int quad = lane >> 4;
    const int cl   = lane & 15;
    const int m0 = blockIdx.y * 64;
    const int n0 = blockIdx.x * 128;
    const int wm = (wid & 1) * 32;
    const int wn = (wid >> 1) * 64;

    const int srow = lane >> 2;
    const int scol = (lane & 3) * 8;

    f32x4 acc[2][4];
#pragma unroll
    for (int i = 0; i < 2; ++i)
#pragma unroll
        for (int j = 0; j < 4; ++j) acc[i][j] = (f32x4){0.f, 0.f, 0.f, 0.f};

    for (int k0 = 0; k0 < K; k0 += 32) {
#pragma unroll
        for (int c = 0; c < 3; ++c) {
            const int cid = wid * 3 + c;          // 0..11
            const ushort* s; ushort* d; int rr;
            if (cid < 4) { s = A_g; d = AS + cid * 512; rr = m0 + cid * 16; }
            else         { s = W_g; d = WS + (cid - 4) * 512; rr = n0 + (cid - 4) * 16; }
            gl_lds16(s + (size_t)(rr + srow) * K + k0 + scol, d);
        }
        __syncthreads();

        f16x8 ah[2], wh[4];
#pragma unroll
        for (int i = 0; i < 2; ++i)
            ah[i] = ((const f16x8*)AS)[(wm + i * 16 + cl) * 4 + quad];
#pragma unroll
        for (int i = 0; i < 4; ++i)
            wh[i] = ((const f16x8*)WS)[(wn + i * 16 + cl) * 4 + quad];
#pragma unroll
        for (int mi = 0; mi < 2; ++mi)
#pragma unroll
            for (int ni = 0; ni < 4; ++ni)
                acc[mi][ni] = MFMA16(ah[mi], wh[ni], acc[mi][ni]);
        __syncthreads();
    }

    float bb[4];
#pragma unroll
    for (int ni = 0; ni < 4; ++ni) bb[ni] = bias[n0 + wn + ni * 16 + cl];
#pragma unroll
    for (int mi = 0; mi < 2; ++mi)
#pragma unroll
        for (int r = 0; r < 4; ++r) {
            const int gm = m0 + wm + mi * 16 + quad * 4 + r;
            float* rowp = out + (size_t)gm * Nout;
#pragma unroll
            for (int ni = 0; ni < 4; ++ni) {
                const int gn = n0 + wn + ni * 16 + cl;
                rowp[gn] = acc[mi][ni][r] + bb[ni];
            }
        }
}

// ---------------------------------------------------------------------------
// MFMA flash-band attention (fp16) with FUSED S_all. Block = one (b,h) x 64
// q-rows, 4 waves x 16 rows. Rows are 136 cols (272B): start-bank rotation 4
// -> 2-way aliasing on b128 frag reads (free), vs 4-way at 144.
// ---------------------------------------------------------------------------
__global__ __launch_bounds__(256) void attn_mfma(
    const ushort* __restrict__ qg, const ushort* __restrict__ kg,
    const ushort* __restrict__ vg,
    ushort* __restrict__ outp,
    const int* __restrict__ epoch_ptr)
{
    const int N = 2048;
    const int w = (epoch_ptr[0] < 15) ? 16 : 20;

    __shared__ ushort Pl[4][16][136];     // per-wave P~ tile (cols 0..128 read)
    __shared__ ushort VT[64][136];        // transposed V band [dim][seq]
    __shared__ _Float16 SallRed[32][64];  // per-group partial column sums
    __shared__ float Sfin[64];            // final S_all

    const int tid  = threadIdx.x;
    const int wid  = tid >> 6;
    const int lane = tid & 63;
    const int quad = lane >> 4;
    const int cl   = lane & 15;

    const int bh = blockIdx.x >> 5;
    const int n0 = (blockIdx.x & 31) << 6;
    const int lo = max(0, n0 - w);
    const int wm = wid * 16;
    const int hi = min(N - 1, n0 + 63 + w);
    const int cnt = hi - lo + 1;        // 80..104 (scatter always fills <64)

    // zero VT cols [64,136) only (cnt >= 80 guarantees cols <64 get filled)
    for (int t = tid; t < 64 * 36; t += 256) {
        const int row = t / 36;
        const int c2  = 64 + (t - row * 36) * 2;
        *(unsigned*)&VT[row][c2] = 0u;
    }

    // fused S_all partials: group g = tid>>3 owns rows g, g+32, ...;
    // slice ds = tid&7 owns dims ds*8..ds*8+8 (fp16 pair accumulation).
    {
        const int ds = tid & 7;
        const int grp = tid >> 3;
        const ushort* vp = vg + ((size_t)bh * N + grp) * 64 + ds * 8;
        f16x8 vacc = (f16x8){0, 0, 0, 0, 0, 0, 0, 0};
#pragma unroll 8
        for (int it = 0; it < 64; ++it)
            vacc = vacc + *(const f16x8*)(vp + (size_t)it * 32 * 64);
        *(f16x8*)&SallRed[grp][ds * 8] = vacc;
    }
    __syncthreads();    // VT zero + SallRed partials complete

    // wave 0 folds the 32 partials into Sfin while others stage VT
    if (tid < 64) {
        float s = 0.f;
#pragma unroll
        for (int j = 0; j < 32; ++j) s += (float)SallRed[j][tid];
        Sfin[tid] = s;
    }

    // scatter V band (coalesced reads) into VT transposed
    for (int t = tid; t < 104 * 8; t += 256) {
        const int s  = t >> 3;
        const int db = (t & 7) * 8;
        if (s < cnt) {
            uint4 vv = *(const uint4*)(vg + (((size_t)bh * N) + lo + s) * 64 + db);
            VT[db + 0][s] = (ushort)(vv.x & 0xffff); VT[db + 1][s] = (ushort)(vv.x >> 16);
            VT[db + 2][s] = (ushort)(vv.y & 0xffff); VT[db + 3][s] = (ushort)(vv.y >> 16);
            VT[db + 4][s] = (ushort)(vv.z & 0xffff); VT[db + 5][s] = (ushort)(vv.z >> 16);
            VT[db + 6][s] = (ushort)(vv.w & 0xffff); VT[db + 7][s] = (ushort)(vv.w >> 16);
        }
    }
    // (no barrier yet: S/softmax below overlaps the scatter; barrier before PV)

    // Q A-frags straight from global (lane cl = row, quad = k-offset)
    const ushort* qp = qg + ((size_t)bh * N + n0 + wm + cl) * 64;
    const f16x8 aq0 = *(const f16x8*)(qp + quad * 8);
    const f16x8 aq1 = *(const f16x8*)(qp + 32 + quad * 8);

    // S tiles: 7 ni x (K=64 in 2 steps)
    f32x4 sacc[7];
#pragma unroll
    for (int ni = 0; ni < 7; ++ni) {
        int krow = lo + ni * 16 + cl;
        krow = min(krow, N - 1);                 // clamped rows masked later
        const ushort* kp = kg + ((size_t)bh * N + krow) * 64;
        const f16x8 bk0 = *(const f16x8*)(kp + quad * 8);
        const f16x8 bk1 = *(const f16x8*)(kp + 32 + quad * 8);
        f32x4 s = (f32x4){0.f, 0.f, 0.f, 0.f};
        s = MFMA16(aq0, bk0, s);
        s = MFMA16(aq1, bk1, s);
        sacc[ni] = s;
    }

    // softmax per row r (C-layout: row = quad*4+r, col = ni*16+cl)
    float pm[4];
#pragma unroll
    for (int r = 0; r < 4; ++r) {
        const int n = n0 + wm + quad * 4 + r;
        const int jlo = max(0, n - w), jhi = min(N - 1, n + w);
        const int bc = jhi - jlo + 1;
        float mx = 1e-9f;
#pragma unroll
        for (int ni = 0; ni < 7; ++ni) {
            const int j = lo + ni * 16 + cl;
            const bool val = (j >= n - w) && (j <= n + w) && (j < N);
            const float sv = 4.0f * sacc[ni][r];
            if (val) mx = fmaxf(mx, sv);
        }
        mx = fmaxf(mx, __shfl_xor(mx, 1));
        mx = fmaxf(mx, __shfl_xor(mx, 2));
        mx = fmaxf(mx, __shfl_xor(mx, 4));
        mx = fmaxf(mx, __shfl_xor(mx, 8));
        const float em = __expf(1e-9f - mx);
        float e[7];
        float sum = 0.f;
#pragma unroll
        for (int ni = 0; ni < 7; ++ni) {
            const int j = lo + ni * 16 + cl;
            const bool val = (j >= n - w) && (j <= n + w) && (j < N);
            const float ev = val ? __expf(4.0f * sacc[ni][r] - mx) : 0.f;
            e[ni] = val ? (ev - em) : 0.f;
            sum += ev;
        }
        sum += __shfl_xor(sum, 1);
        sum += __shfl_xor(sum, 2);
        sum += __shfl_xor(sum, 4);
        sum += __shfl_xor(sum, 8);
        const float inv = 1.0f / ((float)(N - bc) * em + sum);
        pm[r] = em * inv;
#pragma unroll
        for (int ni = 0; ni < 7; ++ni)
            sacc[ni][r] = e[ni] * inv;           // P~ = (e - em)/denom
    }

    // P~ -> LDS fp16 (same-wave slice) + zero the k-pad cols [112,128)
#pragma unroll
    for (int ni = 0; ni < 7; ++ni)
#pragma unroll
        for (int r = 0; r < 4; ++r)
            Pl[wid][quad * 4 + r][ni * 16 + cl] = f2h(sacc[ni][r]);
    {
        const int prow = lane >> 2;
        const int pc = 112 + (lane & 3) * 4;
        *(uint2*)&Pl[wid][prow][pc] = make_uint2(0u, 0u);
    }

    __syncthreads();   // VT scatter + Sfin complete (P~ safely ordered)

    // PV: out(16 rows x 64 dims) = P~ (16x128) . Vband (128x64)
    const int b = bh >> 4, h = bh & 15;
#pragma unroll
    for (int dn = 0; dn < 4; ++dn) {
        f32x4 o = (f32x4){0.f, 0.f, 0.f, 0.f};
#pragma unroll
        for (int k0 = 0; k0 < 128; k0 += 32) {
            const f16x8 a  = *(const f16x8*)&Pl[wid][cl][k0 + quad * 8];
            const f16x8 bb = *(const f16x8*)&VT[dn * 16 + cl][k0 + quad * 8];
            o = MFMA16(a, bb, o);
        }
        const int d = dn * 16 + cl;
        const float sv = Sfin[d];
#pragma unroll
        for (int r = 0; r < 4; ++r) {
            const int n = n0 + wm + quad * 4 + r;
            outp[((size_t)b * N + n) * 1024 + h * 64 + d] = f2h(o[r] + pm[r] * sv);
        }
    }
}

extern "C" void kernel_launch(void* const* d_in, const int* in_sizes, int n_in,
                              void* d_out, int out_size, void* d_ws, size_t ws_size,
                              hipStream_t stream)
{
    const float* x      = (const float*)d_in[0];
    const float* qkv_w  = (const float*)d_in[1];
    const float* proj_w = (const float*)d_in[2];
    const float* proj_b = (const float*)d_in[3];
    const int*   epoch  = (const int*)d_in[4];
    float* out = (float*)d_out;

    const size_t BHND = (size_t)2 * 16 * 2048 * 64;   // 4,194,304
    const size_t XN = 4194304, WN = 3145728;

    ushort* qkv16 = (ushort*)d_ws;            // q|k|v fp16, contiguous
    ushort* q16   = qkv16;
    ushort* k16   = qkv16 + BHND;
    ushort* v16   = qkv16 + 2 * BHND;
    ushort* x16   = qkv16 + 3 * BHND;
    ushort* w16   = x16 + XN;
    ushort* pw16  = w16 + WN;
    ushort* ao    = x16;   // alias: x16 dead after qkv gemm

    split_all<<<dim3(8192), dim3(256), 0, stream>>>(x, qkv_w, proj_w, x16, w16, pw16);

    gemm_mfma<<<dim3(24, 32), dim3(256), 0, stream>>>(x16, w16, qkv16, 1024);

    attn_mfma<<<dim3(1024), dim3(256), 0, stream>>>(q16, k16, v16, ao, epoch);

    gemm_proj<<<dim3(8, 64), dim3(256), 0, stream>>>(ao, pw16, proj_b, out);
}

// Round 13
// 161.311 us; speedup vs baseline: 1.2919x; 1.0407x over previous
//
#include <hip/hip_runtime.h>
#include <cstddef>

// ---------------------------------------------------------------------------
// B=2, N=2048, C=1024, H=16, Dh=64, scale = Dh//H = 4
// 4-launch ALL-FP16 pipeline:
//   split_all:  x, qkv_w, proj_w -> fp16 (one launch)
//   gemm_mfma:  qkv GEMM, 128x128 tile, BK=64 as two [rows][32] K-planes
//               (halves barrier count vs BK=32; keeps proven 64B-stride LDS
//               addressing + gl_lds16 staging) -> q|k|v fp16 [3][B,H,N,64]
//   attn_mfma:  S=QK^T fp16 MFMA, exact full-row softmax w/ masked-logit
//               (=1e-9) fold, fused S_all, P fp16 -> PV MFMA vs LDS V^T band
//   gemm_proj:  64x128 tiles, BK=64 two-plane, fp16 MFMA + bias -> fp32 out
// NOTE: no LDS-pointer arrays (addrspacecast-in-initializer is rejected by
// gfx950 codegen) — plane pointers computed by direct arithmetic.
// ---------------------------------------------------------------------------

typedef _Float16 f16x8 __attribute__((ext_vector_type(8)));
typedef float    f32x4 __attribute__((ext_vector_type(4)));

#define MFMA16(a, b, c) __builtin_amdgcn_mfma_f32_16x16x32_f16((a), (b), (c), 0, 0, 0)

__device__ __forceinline__ void gl_lds16(const void* g, void* l) {
    __builtin_amdgcn_global_load_lds(
        (const __attribute__((address_space(1))) void*)g,
        (__attribute__((address_space(3))) void*)l, 16, 0, 0);
}

__device__ __forceinline__ ushort f2h(float f) {
    _Float16 h = (_Float16)f;
    return *(ushort*)&h;
}

// ---------------------------------------------------------------------------
// fused fp32 -> fp16 conversion for all three tensors in one launch.
// ---------------------------------------------------------------------------
__global__ void split_all(const float* __restrict__ x,
                          const float* __restrict__ qkvw,
                          const float* __restrict__ projw,
                          ushort* __restrict__ x16,
                          ushort* __restrict__ w16,
                          ushort* __restrict__ pw16)
{
    const int i = blockIdx.x * 256 + threadIdx.x;
    const float* src; ushort* dst; int j;
    if (i < 1048576)      { src = x;     dst = x16;  j = i; }
    else if (i < 1835008) { src = qkvw;  dst = w16;  j = i - 1048576; }
    else                  { src = projw; dst = pw16; j = i - 1835008; }

    float4 v = ((const float4*)src)[j];
    ((ushort4*)dst)[j] = make_ushort4(f2h(v.x), f2h(v.y), f2h(v.z), f2h(v.w));
}

// ---------------------------------------------------------------------------
// qkv MFMA GEMM: 128x128 tile, BK=64 stored as two [128][32] fp16 planes per
// operand (A0,A1,W0,W1; 32 KB). Wave w stages plane w (8 x 1KB chunks).
// 16 K-iters x 32 MFMA/wave. Scatter fp16 into q|k|v [3][B,H,N,64].
// ---------------------------------------------------------------------------
__global__ __launch_bounds__(256, 3) void gemm_mfma(
    const ushort* __restrict__ A_g, const ushort* __restrict__ W_g,
    ushort* __restrict__ out16, int K)
{
    __shared__ ushort smem[16384];
    ushort* AS0 = smem;
    ushort* AS1 = smem + 4096;
    ushort* WS0 = smem + 8192;
    ushort* WS1 = smem + 12288;

    const int tid  = threadIdx.x;
    const int wid  = tid >> 6;
    const int lane = tid & 63;
    const int quad = lane >> 4;
    const int cl   = lane & 15;
    const int m0 = blockIdx.y * 128;
    const int n0 = blockIdx.x * 128;
    const int wm = (wid & 1) * 64;
    const int wn = (wid >> 1) * 64;

    const int srow = lane >> 2;
    const int scol = (lane & 3) * 8;

    // wave w stages: w=0 A-plane0, w=1 A-plane1, w=2 W-plane0, w=3 W-plane1
    const ushort* src = (wid < 2) ? A_g : W_g;
    ushort* dst = smem + wid * 4096;
    const int r0 = (wid < 2) ? m0 : n0;
    const int cofs = (wid & 1) * 32;     // k-plane offset

    f32x4 acc[4][4];
#pragma unroll
    for (int i = 0; i < 4; ++i)
#pragma unroll
        for (int j = 0; j < 4; ++j) acc[i][j] = (f32x4){0.f, 0.f, 0.f, 0.f};

    for (int k0 = 0; k0 < K; k0 += 64) {
#pragma unroll
        for (int c = 0; c < 8; ++c)
            gl_lds16(src + (size_t)(r0 + c * 16 + srow) * K + k0 + cofs + scol,
                     dst + c * 512);
        __syncthreads();

        f16x8 a0[4], w0[4];
#pragma unroll
        for (int i = 0; i < 4; ++i) {
            a0[i] = ((const f16x8*)AS0)[(wm + i * 16 + cl) * 4 + quad];
            w0[i] = ((const f16x8*)WS0)[(wn + i * 16 + cl) * 4 + quad];
        }
#pragma unroll
        for (int mi = 0; mi < 4; ++mi)
#pragma unroll
            for (int ni = 0; ni < 4; ++ni)
                acc[mi][ni] = MFMA16(a0[mi], w0[ni], acc[mi][ni]);

        f16x8 a1[4], w1[4];
#pragma unroll
        for (int i = 0; i < 4; ++i) {
            a1[i] = ((const f16x8*)AS1)[(wm + i * 16 + cl) * 4 + quad];
            w1[i] = ((const f16x8*)WS1)[(wn + i * 16 + cl) * 4 + quad];
        }
#pragma unroll
        for (int mi = 0; mi < 4; ++mi)
#pragma unroll
            for (int ni = 0; ni < 4; ++ni)
                acc[mi][ni] = MFMA16(a1[mi], w1[ni], acc[mi][ni]);
        __syncthreads();
    }

#pragma unroll
    for (int mi = 0; mi < 4; ++mi)
#pragma unroll
        for (int r = 0; r < 4; ++r) {
            const int gm = m0 + wm + mi * 16 + quad * 4 + r;
            const int b  = gm >> 11;
            const int nn = gm & 2047;
#pragma unroll
            for (int ni = 0; ni < 4; ++ni) {
                const int gn = n0 + wn + ni * 16 + cl;
                const int s  = gn >> 10;          // 0:q 1:k 2:v
                const int h  = (gn >> 6) & 15;
                const int dh = gn & 63;
                out16[(size_t)s * 4194304u + (((size_t)b * 16 + h) * 2048 + nn) * 64 + dh]
                    = f2h(acc[mi][ni][r]);
            }
        }
}

// ---------------------------------------------------------------------------
// Proj GEMM, 64x128 tiles (512 blocks = 2/CU), BK=64 two-plane (24 KB LDS).
// Chunks: A0:0-3, A1:4-7, W0:8-15, W1:16-23; wave stages 6. 16 iters x
// 16 MFMA/wave.
// ---------------------------------------------------------------------------
__global__ __launch_bounds__(256, 3) void gemm_proj(
    const ushort* __restrict__ A_g, const ushort* __restrict__ W_g,
    const float* __restrict__ bias, float* __restrict__ out)
{
    const int K = 1024, Nout = 1024;
    __shared__ ushort smem[12288];
    ushort* AS0 = smem;            // [64][32]
    ushort* AS1 = smem + 2048;
    ushort* WS0 = smem + 4096;     // [128][32]
    ushort* WS1 = smem + 8192;

    const int tid  = threadIdx.x;
    const int wid  = tid >> 6;
    const int lane = tid & 63;
    const int quad = lane >> 4;
    const int cl   = lane & 15;
    const int m0 = blockIdx.y * 64;
    const int n0 = blockIdx.x * 128;
    const int wm = (wid & 1) * 32;
    const int wn = (wid >> 1) * 64;

    const int srow = lane >> 2;
    const int scol = (lane & 3) * 8;

    f32x4 acc[2][4];
#pragma unroll
    for (int i = 0; i < 2; ++i)
#pragma unroll
        for (int j = 0; j < 4; ++j) acc[i][j] = (f32x4){0.f, 0.f, 0.f, 0.f};

    for (int k0 = 0; k0 < K; k0 += 64) {
#pragma unroll
        for (int c = 0; c < 6; ++c) {
            const int cid = wid * 6 + c;          // 0..23
            const ushort* s; ushort* d; int rr, pl;
            if (cid < 4)       { s = A_g; d = AS0 + cid * 512;        rr = m0 + cid * 16;        pl = 0; }
            else if (cid < 8)  { s = A_g; d = AS1 + (cid - 4) * 512;  rr = m0 + (cid - 4) * 16;  pl = 1; }
            else if (cid < 16) { s = W_g; d = WS0 + (cid - 8) * 512;  rr = n0 + (cid - 8) * 16;  pl = 0; }
            else               { s = W_g; d = WS1 + (cid - 16) * 512; rr = n0 + (cid - 16) * 16; pl = 1; }
            gl_lds16(s + (size_t)(rr + srow) * K + k0 + pl * 32 + scol, d);
        }
        __syncthreads();

        f16x8 a0[2], w0[4];
#pragma unroll
        for (int i = 0; i < 2; ++i)
            a0[i] = ((const f16x8*)AS0)[(wm + i * 16 + cl) * 4 + quad];
#pragma unroll
        for (int i = 0; i < 4; ++i)
            w0[i] = ((const f16x8*)WS0)[(wn + i * 16 + cl) * 4 + quad];
#pragma unroll
        for (int mi = 0; mi < 2; ++mi)
#pragma unroll
            for (int ni = 0; ni < 4; ++ni)
                acc[mi][ni] = MFMA16(a0[mi], w0[ni], acc[mi][ni]);

        f16x8 a1[2], w1[4];
#pragma unroll
        for (int i = 0; i < 2; ++i)
            a1[i] = ((const f16x8*)AS1)[(wm + i * 16 + cl) * 4 + quad];
#pragma unroll
        for (int i = 0; i < 4; ++i)
            w1[i] = ((const f16x8*)WS1)[(wn + i * 16 + cl) * 4 + quad];
#pragma unroll
        for (int mi = 0; mi < 2; ++mi)
#pragma unroll
            for (int ni = 0; ni < 4; ++ni)
                acc[mi][ni] = MFMA16(a1[mi], w1[ni], acc[mi][ni]);
        __syncthreads();
    }

    float bb[4];
#pragma unroll
    for (int ni = 0; ni < 4; ++ni) bb[ni] = bias[n0 + wn + ni * 16 + cl];
#pragma unroll
    for (int mi = 0; mi < 2; ++mi)
#pragma unroll
        for (int r = 0; r < 4; ++r) {
            const int gm = m0 + wm + mi * 16 + quad * 4 + r;
            float* rowp = out + (size_t)gm * Nout;
#pragma unroll
            for (int ni = 0; ni < 4; ++ni) {
                const int gn = n0 + wn + ni * 16 + cl;
                rowp[gn] = acc[mi][ni][r] + bb[ni];
            }
        }
}

// ---------------------------------------------------------------------------
// MFMA flash-band attention (fp16) with FUSED S_all. Block = one (b,h) x 64
// q-rows, 4 waves x 16 rows. Rows are 136 cols (272B): 2-way bank aliasing.
// ---------------------------------------------------------------------------
__global__ __launch_bounds__(256) void attn_mfma(
    const ushort* __restrict__ qg, const ushort* __restrict__ kg,
    const ushort* __restrict__ vg,
    ushort* __restrict__ outp,
    const int* __restrict__ epoch_ptr)
{
    const int N = 2048;
    const int w = (epoch_ptr[0] < 15) ? 16 : 20;

    __shared__ ushort Pl[4][16][136];     // per-wave P~ tile (cols 0..128 read)
    __shared__ ushort VT[64][136];        // transposed V band [dim][seq]
    __shared__ _Float16 SallRed[32][64];  // per-group partial column sums
    __shared__ float Sfin[64];            // final S_all

    const int tid  = threadIdx.x;
    const int wid  = tid >> 6;
    const int lane = tid & 63;
    const int quad = lane >> 4;
    const int cl   = lane & 15;

    const int bh = blockIdx.x >> 5;
    const int n0 = (blockIdx.x & 31) << 6;
    const int lo = max(0, n0 - w);
    const int wm = wid * 16;
    const int hi = min(N - 1, n0 + 63 + w);
    const int cnt = hi - lo + 1;        // 80..104

    // zero VT cols [64,136) only (cnt >= 80 guarantees cols <64 get filled)
    for (int t = tid; t < 64 * 36; t += 256) {
        const int row = t / 36;
        const int c2  = 64 + (t - row * 36) * 2;
        *(unsigned*)&VT[row][c2] = 0u;
    }

    // fused S_all partials (fp16 pair accumulation)
    {
        const int ds = tid & 7;
        const int grp = tid >> 3;
        const ushort* vp = vg + ((size_t)bh * N + grp) * 64 + ds * 8;
        f16x8 vacc = (f16x8){0, 0, 0, 0, 0, 0, 0, 0};
#pragma unroll 8
        for (int it = 0; it < 64; ++it)
            vacc = vacc + *(const f16x8*)(vp + (size_t)it * 32 * 64);
        *(f16x8*)&SallRed[grp][ds * 8] = vacc;
    }
    __syncthreads();    // VT zero + SallRed partials complete

    if (tid < 64) {
        float s = 0.f;
#pragma unroll
        for (int j = 0; j < 32; ++j) s += (float)SallRed[j][tid];
        Sfin[tid] = s;
    }

    // scatter V band (coalesced reads) into VT transposed
    for (int t = tid; t < 104 * 8; t += 256) {
        const int s  = t >> 3;
        const int db = (t & 7) * 8;
        if (s < cnt) {
            uint4 vv = *(const uint4*)(vg + (((size_t)bh * N) + lo + s) * 64 + db);
            VT[db + 0][s] = (ushort)(vv.x & 0xffff); VT[db + 1][s] = (ushort)(vv.x >> 16);
            VT[db + 2][s] = (ushort)(vv.y & 0xffff); VT[db + 3][s] = (ushort)(vv.y >> 16);
            VT[db + 4][s] = (ushort)(vv.z & 0xffff); VT[db + 5][s] = (ushort)(vv.z >> 16);
            VT[db + 6][s] = (ushort)(vv.w & 0xffff); VT[db + 7][s] = (ushort)(vv.w >> 16);
        }
    }

    const ushort* qp = qg + ((size_t)bh * N + n0 + wm + cl) * 64;
    const f16x8 aq0 = *(const f16x8*)(qp + quad * 8);
    const f16x8 aq1 = *(const f16x8*)(qp + 32 + quad * 8);

    f32x4 sacc[7];
#pragma unroll
    for (int ni = 0; ni < 7; ++ni) {
        int krow = lo + ni * 16 + cl;
        krow = min(krow, N - 1);
        const ushort* kp = kg + ((size_t)bh * N + krow) * 64;
        const f16x8 bk0 = *(const f16x8*)(kp + quad * 8);
        const f16x8 bk1 = *(const f16x8*)(kp + 32 + quad * 8);
        f32x4 s = (f32x4){0.f, 0.f, 0.f, 0.f};
        s = MFMA16(aq0, bk0, s);
        s = MFMA16(aq1, bk1, s);
        sacc[ni] = s;
    }

    float pm[4];
#pragma unroll
    for (int r = 0; r < 4; ++r) {
        const int n = n0 + wm + quad * 4 + r;
        const int jlo = max(0, n - w), jhi = min(N - 1, n + w);
        const int bc = jhi - jlo + 1;
        float mx = 1e-9f;
#pragma unroll
        for (int ni = 0; ni < 7; ++ni) {
            const int j = lo + ni * 16 + cl;
            const bool val = (j >= n - w) && (j <= n + w) && (j < N);
            const float sv = 4.0f * sacc[ni][r];
            if (val) mx = fmaxf(mx, sv);
        }
        mx = fmaxf(mx, __shfl_xor(mx, 1));
        mx = fmaxf(mx, __shfl_xor(mx, 2));
        mx = fmaxf(mx, __shfl_xor(mx, 4));
        mx = fmaxf(mx, __shfl_xor(mx, 8));
        const float em = __expf(1e-9f - mx);
        float e[7];
        float sum = 0.f;
#pragma unroll
        for (int ni = 0; ni < 7; ++ni) {
            const int j = lo + ni * 16 + cl;
            const bool val = (j >= n - w) && (j <= n + w) && (j < N);
            const float ev = val ? __expf(4.0f * sacc[ni][r] - mx) : 0.f;
            e[ni] = val ? (ev - em) : 0.f;
            sum += ev;
        }
        sum += __shfl_xor(sum, 1);
        sum += __shfl_xor(sum, 2);
        sum += __shfl_xor(sum, 4);
        sum += __shfl_xor(sum, 8);
        const float inv = 1.0f / ((float)(N - bc) * em + sum);
        pm[r] = em * inv;
#pragma unroll
        for (int ni = 0; ni < 7; ++ni)
            sacc[ni][r] = e[ni] * inv;           // P~ = (e - em)/denom
    }

#pragma unroll
    for (int ni = 0; ni < 7; ++ni)
#pragma unroll
        for (int r = 0; r < 4; ++r)
            Pl[wid][quad * 4 + r][ni * 16 + cl] = f2h(sacc[ni][r]);
    {
        const int prow = lane >> 2;
        const int pc = 112 + (lane & 3) * 4;
        *(uint2*)&Pl[wid][prow][pc] = make_uint2(0u, 0u);
    }

    __syncthreads();   // VT scatter + Sfin complete

    const int b = bh >> 4, h = bh & 15;
#pragma unroll
    for (int dn = 0; dn < 4; ++dn) {
        f32x4 o = (f32x4){0.f, 0.f, 0.f, 0.f};
#pragma unroll
        for (int k0 = 0; k0 < 128; k0 += 32) {
            const f16x8 a  = *(const f16x8*)&Pl[wid][cl][k0 + quad * 8];
            const f16x8 bb = *(const f16x8*)&VT[dn * 16 + cl][k0 + quad * 8];
            o = MFMA16(a, bb, o);
        }
        const int d = dn * 16 + cl;
        const float sv = Sfin[d];
#pragma unroll
        for (int r = 0; r < 4; ++r) {
            const int n = n0 + wm + quad * 4 + r;
            outp[((size_t)b * N + n) * 1024 + h * 64 + d] = f2h(o[r] + pm[r] * sv);
        }
    }
}

extern "C" void kernel_launch(void* const* d_in, const int* in_sizes, int n_in,
                              void* d_out, int out_size, void* d_ws, size_t ws_size,
                              hipStream_t stream)
{
    const float* x      = (const float*)d_in[0];
    const float* qkv_w  = (const float*)d_in[1];
    const float* proj_w = (const float*)d_in[2];
    const float* proj_b = (const float*)d_in[3];
    const int*   epoch  = (const int*)d_in[4];
    float* out = (float*)d_out;

    const size_t BHND = (size_t)2 * 16 * 2048 * 64;   // 4,194,304
    const size_t XN = 4194304, WN = 3145728;

    ushort* qkv16 = (ushort*)d_ws;            // q|k|v fp16, contiguous
    ushort* q16   = qkv16;
    ushort* k16   = qkv16 + BHND;
    ushort* v16   = qkv16 + 2 * BHND;
    ushort* x16   = qkv16 + 3 * BHND;
    ushort* w16   = x16 + XN;
    ushort* pw16  = w16 + WN;
    ushort* ao    = x16;   // alias: x16 dead after qkv gemm

    split_all<<<dim3(8192), dim3(256), 0, stream>>>(x, qkv_w, proj_w, x16, w16, pw16);

    gemm_mfma<<<dim3(24, 32), dim3(256), 0, stream>>>(x16, w16, qkv16, 1024);

    attn_mfma<<<dim3(1024), dim3(256), 0, stream>>>(q16, k16, v16, ao, epoch);

    gemm_proj<<<dim3(8, 64), dim3(256), 0, stream>>>(ao, pw16, proj_b, out);
}

// Round 14
// 152.241 us; speedup vs baseline: 1.3689x; 1.0596x over previous
//
#include <hip/hip_runtime.h>
#include <cstddef>

// ---------------------------------------------------------------------------
// B=2, N=2048, C=1024, H=16, Dh=64, scale = Dh//H = 4
// 4-launch ALL-FP16 pipeline:
//   split_all:  x, qkv_w, proj_w -> fp16 (one launch)
//   gemm_mfma:  qkv GEMM, 128x128 tile, BK=64 two-plane; v-blocks also
//               atomically accumulate S_all column sums (fp32) in epilogue
//   attn_mfma:  S=QK^T fp16 MFMA, exact full-row softmax w/ masked-logit
//               (=1e-9) fold, P fp16 -> PV MFMA vs LDS V^T band; S_all read
//               from global (computed by qkv epilogue)
//   gemm_proj:  64x128 tiles, BK=128 four-plane (8 iters x 32 MFMA; grid
//               already caps occupancy at 2/CU so 48KB LDS is free)
// ---------------------------------------------------------------------------

typedef _Float16 f16x8 __attribute__((ext_vector_type(8)));
typedef float    f32x4 __attribute__((ext_vector_type(4)));

#define MFMA16(a, b, c) __builtin_amdgcn_mfma_f32_16x16x32_f16((a), (b), (c), 0, 0, 0)

__device__ __forceinline__ void gl_lds16(const void* g, void* l) {
    __builtin_amdgcn_global_load_lds(
        (const __attribute__((address_space(1))) void*)g,
        (__attribute__((address_space(3))) void*)l, 16, 0, 0);
}

__device__ __forceinline__ ushort f2h(float f) {
    _Float16 h = (_Float16)f;
    return *(ushort*)&h;
}

// ---------------------------------------------------------------------------
// fused fp32 -> fp16 conversion for all three tensors in one launch.
// ---------------------------------------------------------------------------
__global__ void split_all(const float* __restrict__ x,
                          const float* __restrict__ qkvw,
                          const float* __restrict__ projw,
                          ushort* __restrict__ x16,
                          ushort* __restrict__ w16,
                          ushort* __restrict__ pw16)
{
    const int i = blockIdx.x * 256 + threadIdx.x;
    const float* src; ushort* dst; int j;
    if (i < 1048576)      { src = x;     dst = x16;  j = i; }
    else if (i < 1835008) { src = qkvw;  dst = w16;  j = i - 1048576; }
    else                  { src = projw; dst = pw16; j = i - 1835008; }

    float4 v = ((const float4*)src)[j];
    ((ushort4*)dst)[j] = make_ushort4(f2h(v.x), f2h(v.y), f2h(v.z), f2h(v.w));
}

// ---------------------------------------------------------------------------
// qkv MFMA GEMM: 128x128 tile, BK=64 two-plane (32 KB). 16 iters x 32 MFMA.
// Scatter fp16 into q|k|v [3][B,H,N,64]. v-blocks (n0>=2048) also reduce
// their 64-row column partials and atomicAdd into sall[32][64] (fp32).
// ---------------------------------------------------------------------------
__global__ __launch_bounds__(256, 3) void gemm_mfma(
    const ushort* __restrict__ A_g, const ushort* __restrict__ W_g,
    ushort* __restrict__ out16, float* __restrict__ sall, int K)
{
    __shared__ ushort smem[16384];
    ushort* AS0 = smem;
    ushort* AS1 = smem + 4096;
    ushort* WS0 = smem + 8192;
    ushort* WS1 = smem + 12288;

    const int tid  = threadIdx.x;
    const int wid  = tid >> 6;
    const int lane = tid & 63;
    const int quad = lane >> 4;
    const int cl   = lane & 15;
    const int m0 = blockIdx.y * 128;
    const int n0 = blockIdx.x * 128;
    const int wm = (wid & 1) * 64;
    const int wn = (wid >> 1) * 64;

    const int srow = lane >> 2;
    const int scol = (lane & 3) * 8;

    const ushort* src = (wid < 2) ? A_g : W_g;
    ushort* dst = smem + wid * 4096;
    const int r0 = (wid < 2) ? m0 : n0;
    const int cofs = (wid & 1) * 32;

    f32x4 acc[4][4];
#pragma unroll
    for (int i = 0; i < 4; ++i)
#pragma unroll
        for (int j = 0; j < 4; ++j) acc[i][j] = (f32x4){0.f, 0.f, 0.f, 0.f};

    for (int k0 = 0; k0 < K; k0 += 64) {
#pragma unroll
        for (int c = 0; c < 8; ++c)
            gl_lds16(src + (size_t)(r0 + c * 16 + srow) * K + k0 + cofs + scol,
                     dst + c * 512);
        __syncthreads();

        f16x8 a0[4], w0[4];
#pragma unroll
        for (int i = 0; i < 4; ++i) {
            a0[i] = ((const f16x8*)AS0)[(wm + i * 16 + cl) * 4 + quad];
            w0[i] = ((const f16x8*)WS0)[(wn + i * 16 + cl) * 4 + quad];
        }
#pragma unroll
        for (int mi = 0; mi < 4; ++mi)
#pragma unroll
            for (int ni = 0; ni < 4; ++ni)
                acc[mi][ni] = MFMA16(a0[mi], w0[ni], acc[mi][ni]);

        f16x8 a1[4], w1[4];
#pragma unroll
        for (int i = 0; i < 4; ++i) {
            a1[i] = ((const f16x8*)AS1)[(wm + i * 16 + cl) * 4 + quad];
            w1[i] = ((const f16x8*)WS1)[(wn + i * 16 + cl) * 4 + quad];
        }
#pragma unroll
        for (int mi = 0; mi < 4; ++mi)
#pragma unroll
            for (int ni = 0; ni < 4; ++ni)
                acc[mi][ni] = MFMA16(a1[mi], w1[ni], acc[mi][ni]);
        __syncthreads();
    }

#pragma unroll
    for (int mi = 0; mi < 4; ++mi)
#pragma unroll
        for (int r = 0; r < 4; ++r) {
            const int gm = m0 + wm + mi * 16 + quad * 4 + r;
            const int b  = gm >> 11;
            const int nn = gm & 2047;
#pragma unroll
            for (int ni = 0; ni < 4; ++ni) {
                const int gn = n0 + wn + ni * 16 + cl;
                const int s  = gn >> 10;          // 0:q 1:k 2:v
                const int h  = (gn >> 6) & 15;
                const int dh = gn & 63;
                out16[(size_t)s * 4194304u + (((size_t)b * 16 + h) * 2048 + nn) * 64 + dh]
                    = f2h(acc[mi][ni][r]);
            }
        }

    // v-blocks: S_all partials. Wave covers 64 rows (uniform b) x 64 cols
    // (uniform h; dh = ni*16+cl). Sum acc over mi,r then fold quads via shfl.
    if (n0 >= 2048) {
        const int b = (m0 + wm) >> 11;
        const int h = ((n0 + wn) >> 6) & 15;
#pragma unroll
        for (int ni = 0; ni < 4; ++ni) {
            float ps = 0.f;
#pragma unroll
            for (int mi = 0; mi < 4; ++mi)
#pragma unroll
                for (int r = 0; r < 4; ++r) ps += acc[mi][ni][r];
            ps += __shfl_xor(ps, 16);
            ps += __shfl_xor(ps, 32);
            if (quad == 0)
                atomicAdd(&sall[(b * 16 + h) * 64 + ni * 16 + cl], ps);
        }
    }
}

// ---------------------------------------------------------------------------
// Proj GEMM, 64x128 tiles (512 blocks = 2/CU), BK=128 four-plane (48 KB LDS,
// free: grid caps occupancy at 2/CU anyway). 8 iters x 32 MFMA/wave.
// ---------------------------------------------------------------------------
__global__ __launch_bounds__(256, 2) void gemm_proj(
    const ushort* __restrict__ A_g, const ushort* __restrict__ W_g,
    const float* __restrict__ bias, float* __restrict__ out)
{
    const int K = 1024, Nout = 1024;
    __shared__ ushort smem[24576];   // A: 4 planes x [64][32]; W: 4 x [128][32]

    const int tid  = threadIdx.x;
    const int wid  = tid >> 6;
    const int lane = tid & 63;
    const int quad = lane >> 4;
    const int cl   = lane & 15;
    const int m0 = blockIdx.y * 64;
    const int n0 = blockIdx.x * 128;
    const int wm = (wid & 1) * 32;
    const int wn = (wid >> 1) * 64;

    const int srow = lane >> 2;
    const int scol = (lane & 3) * 8;

    f32x4 acc[2][4];
#pragma unroll
    for (int i = 0; i < 2; ++i)
#pragma unroll
        for (int j = 0; j < 4; ++j) acc[i][j] = (f32x4){0.f, 0.f, 0.f, 0.f};

    for (int k0 = 0; k0 < K; k0 += 128) {
#pragma unroll
        for (int c = 0; c < 12; ++c) {
            const int cid = wid * 12 + c;         // 0..47
            const ushort* s; ushort* d; int rr, pl;
            if (cid < 16) {                       // A: plane = cid>>2, chunk = cid&3
                pl = cid >> 2;
                const int ch = cid & 3;
                s = A_g; rr = m0 + ch * 16;
                d = smem + pl * 2048 + ch * 512;
            } else {                              // W: plane = (cid-16)>>3, chunk = &7
                const int wc = cid - 16;
                pl = wc >> 3;
                const int ch = wc & 7;
                s = W_g; rr = n0 + ch * 16;
                d = smem + 8192 + pl * 4096 + ch * 512;
            }
            gl_lds16(s + (size_t)(rr + srow) * K + k0 + pl * 32 + scol, d);
        }
        __syncthreads();

#pragma unroll
        for (int pl = 0; pl < 4; ++pl) {
            const ushort* ASp = smem + pl * 2048;
            const ushort* WSp = smem + 8192 + pl * 4096;
            f16x8 a[2], w[4];
#pragma unroll
            for (int i = 0; i < 2; ++i)
                a[i] = ((const f16x8*)ASp)[(wm + i * 16 + cl) * 4 + quad];
#pragma unroll
            for (int i = 0; i < 4; ++i)
                w[i] = ((const f16x8*)WSp)[(wn + i * 16 + cl) * 4 + quad];
#pragma unroll
            for (int mi = 0; mi < 2; ++mi)
#pragma unroll
                for (int ni = 0; ni < 4; ++ni)
                    acc[mi][ni] = MFMA16(a[mi], w[ni], acc[mi][ni]);
        }
        __syncthreads();
    }

    float bb[4];
#pragma unroll
    for (int ni = 0; ni < 4; ++ni) bb[ni] = bias[n0 + wn + ni * 16 + cl];
#pragma unroll
    for (int mi = 0; mi < 2; ++mi)
#pragma unroll
        for (int r = 0; r < 4; ++r) {
            const int gm = m0 + wm + mi * 16 + quad * 4 + r;
            float* rowp = out + (size_t)gm * Nout;
#pragma unroll
            for (int ni = 0; ni < 4; ++ni) {
                const int gn = n0 + wn + ni * 16 + cl;
                rowp[gn] = acc[mi][ni][r] + bb[ni];
            }
        }
}

// ---------------------------------------------------------------------------
// MFMA flash-band attention (fp16). Block = one (b,h) x 64 q-rows, 4 waves x
// 16 rows. S_all read from global (qkv epilogue). Rows 136 cols: 2-way alias.
// ---------------------------------------------------------------------------
__global__ __launch_bounds__(256) void attn_mfma(
    const ushort* __restrict__ qg, const ushort* __restrict__ kg,
    const ushort* __restrict__ vg,
    const float* __restrict__ sall,
    ushort* __restrict__ outp,
    const int* __restrict__ epoch_ptr)
{
    const int N = 2048;
    const int w = (epoch_ptr[0] < 15) ? 16 : 20;

    __shared__ ushort Pl[4][16][136];     // per-wave P~ tile (cols 0..128 read)
    __shared__ ushort VT[64][136];        // transposed V band [dim][seq]

    const int tid  = threadIdx.x;
    const int wid  = tid >> 6;
    const int lane = tid & 63;
    const int quad = lane >> 4;
    const int cl   = lane & 15;

    const int bh = blockIdx.x >> 5;
    const int n0 = (blockIdx.x & 31) << 6;
    const int lo = max(0, n0 - w);
    const int wm = wid * 16;
    const int hi = min(N - 1, n0 + 63 + w);
    const int cnt = hi - lo + 1;        // 80..104

    // zero VT cols [64,136) only (cnt >= 80 guarantees cols <64 get filled)
    for (int t = tid; t < 64 * 36; t += 256) {
        const int row = t / 36;
        const int c2  = 64 + (t - row * 36) * 2;
        *(unsigned*)&VT[row][c2] = 0u;
    }
    __syncthreads();    // zero visible before scatter overwrites [64,cnt)

    // scatter V band (coalesced reads) into VT transposed
    for (int t = tid; t < 104 * 8; t += 256) {
        const int s  = t >> 3;
        const int db = (t & 7) * 8;
        if (s < cnt) {
            uint4 vv = *(const uint4*)(vg + (((size_t)bh * N) + lo + s) * 64 + db);
            VT[db + 0][s] = (ushort)(vv.x & 0xffff); VT[db + 1][s] = (ushort)(vv.x >> 16);
            VT[db + 2][s] = (ushort)(vv.y & 0xffff); VT[db + 3][s] = (ushort)(vv.y >> 16);
            VT[db + 4][s] = (ushort)(vv.z & 0xffff); VT[db + 5][s] = (ushort)(vv.z >> 16);
            VT[db + 6][s] = (ushort)(vv.w & 0xffff); VT[db + 7][s] = (ushort)(vv.w >> 16);
        }
    }

    const ushort* qp = qg + ((size_t)bh * N + n0 + wm + cl) * 64;
    const f16x8 aq0 = *(const f16x8*)(qp + quad * 8);
    const f16x8 aq1 = *(const f16x8*)(qp + 32 + quad * 8);

    f32x4 sacc[7];
#pragma unroll
    for (int ni = 0; ni < 7; ++ni) {
        int krow = lo + ni * 16 + cl;
        krow = min(krow, N - 1);
        const ushort* kp = kg + ((size_t)bh * N + krow) * 64;
        const f16x8 bk0 = *(const f16x8*)(kp + quad * 8);
        const f16x8 bk1 = *(const f16x8*)(kp + 32 + quad * 8);
        f32x4 s = (f32x4){0.f, 0.f, 0.f, 0.f};
        s = MFMA16(aq0, bk0, s);
        s = MFMA16(aq1, bk1, s);
        sacc[ni] = s;
    }

    float pm[4];
#pragma unroll
    for (int r = 0; r < 4; ++r) {
        const int n = n0 + wm + quad * 4 + r;
        const int jlo = max(0, n - w), jhi = min(N - 1, n + w);
        const int bc = jhi - jlo + 1;
        float mx = 1e-9f;
#pragma unroll
        for (int ni = 0; ni < 7; ++ni) {
            const int j = lo + ni * 16 + cl;
            const bool val = (j >= n - w) && (j <= n + w) && (j < N);
            const float sv = 4.0f * sacc[ni][r];
            if (val) mx = fmaxf(mx, sv);
        }
        mx = fmaxf(mx, __shfl_xor(mx, 1));
        mx = fmaxf(mx, __shfl_xor(mx, 2));
        mx = fmaxf(mx, __shfl_xor(mx, 4));
        mx = fmaxf(mx, __shfl_xor(mx, 8));
        const float em = __expf(1e-9f - mx);
        float e[7];
        float sum = 0.f;
#pragma unroll
        for (int ni = 0; ni < 7; ++ni) {
            const int j = lo + ni * 16 + cl;
            const bool val = (j >= n - w) && (j <= n + w) && (j < N);
            const float ev = val ? __expf(4.0f * sacc[ni][r] - mx) : 0.f;
            e[ni] = val ? (ev - em) : 0.f;
            sum += ev;
        }
        sum += __shfl_xor(sum, 1);
        sum += __shfl_xor(sum, 2);
        sum += __shfl_xor(sum, 4);
        sum += __shfl_xor(sum, 8);
        const float inv = 1.0f / ((float)(N - bc) * em + sum);
        pm[r] = em * inv;
#pragma unroll
        for (int ni = 0; ni < 7; ++ni)
            sacc[ni][r] = e[ni] * inv;           // P~ = (e - em)/denom
    }

#pragma unroll
    for (int ni = 0; ni < 7; ++ni)
#pragma unroll
        for (int r = 0; r < 4; ++r)
            Pl[wid][quad * 4 + r][ni * 16 + cl] = f2h(sacc[ni][r]);
    {
        const int prow = lane >> 2;
        const int pc = 112 + (lane & 3) * 4;
        *(uint2*)&Pl[wid][prow][pc] = make_uint2(0u, 0u);
    }

    __syncthreads();   // VT scatter complete

    const int b = bh >> 4, h = bh & 15;
#pragma unroll
    for (int dn = 0; dn < 4; ++dn) {
        f32x4 o = (f32x4){0.f, 0.f, 0.f, 0.f};
#pragma unroll
        for (int k0 = 0; k0 < 128; k0 += 32) {
            const f16x8 a  = *(const f16x8*)&Pl[wid][cl][k0 + quad * 8];
            const f16x8 bb = *(const f16x8*)&VT[dn * 16 + cl][k0 + quad * 8];
            o = MFMA16(a, bb, o);
        }
        const int d = dn * 16 + cl;
        const float sv = sall[bh * 64 + d];
#pragma unroll
        for (int r = 0; r < 4; ++r) {
            const int n = n0 + wm + quad * 4 + r;
            outp[((size_t)b * N + n) * 1024 + h * 64 + d] = f2h(o[r] + pm[r] * sv);
        }
    }
}

extern "C" void kernel_launch(void* const* d_in, const int* in_sizes, int n_in,
                              void* d_out, int out_size, void* d_ws, size_t ws_size,
                              hipStream_t stream)
{
    const float* x      = (const float*)d_in[0];
    const float* qkv_w  = (const float*)d_in[1];
    const float* proj_w = (const float*)d_in[2];
    const float* proj_b = (const float*)d_in[3];
    const int*   epoch  = (const int*)d_in[4];
    float* out = (float*)d_out;

    const size_t BHND = (size_t)2 * 16 * 2048 * 64;   // 4,194,304
    const size_t XN = 4194304, WN = 3145728;

    ushort* qkv16 = (ushort*)d_ws;            // q|k|v fp16, contiguous
    ushort* q16   = qkv16;
    ushort* k16   = qkv16 + BHND;
    ushort* v16   = qkv16 + 2 * BHND;
    float*  sall  = (float*)(qkv16 + 3 * BHND);   // 2048 floats (pad 4096)
    ushort* x16   = (ushort*)(sall + 4096);
    ushort* w16   = x16 + XN;
    ushort* pw16  = w16 + WN;
    ushort* ao    = x16;   // alias: x16 dead after qkv gemm

    hipMemsetAsync(sall, 0, 2048 * sizeof(float), stream);

    split_all<<<dim3(8192), dim3(256), 0, stream>>>(x, qkv_w, proj_w, x16, w16, pw16);

    gemm_mfma<<<dim3(24, 32), dim3(256), 0, stream>>>(x16, w16, qkv16, sall, 1024);

    attn_mfma<<<dim3(1024), dim3(256), 0, stream>>>(q16, k16, v16, sall, ao, epoch);

    gemm_proj<<<dim3(8, 64), dim3(256), 0, stream>>>(ao, pw16, proj_b, out);
}

// Round 15
// 149.140 us; speedup vs baseline: 1.3974x; 1.0208x over previous
//
#include <hip/hip_runtime.h>
#include <cstddef>

// ---------------------------------------------------------------------------
// B=2, N=2048, C=1024, H=16, Dh=64, scale = Dh//H = 4
// 4-launch ALL-FP16 pipeline:
//   split_all:  x, qkv_w, proj_w -> fp16 (also zeroes sall; one launch)
//   gemm_mfma:  qkv GEMM, 128x128 tile, BK=64 two-plane; v-blocks also
//               atomically accumulate S_all column sums (fp32) in epilogue
//   attn_mfma:  S=QK^T fp16 MFMA with PER-WAVE 64-wide K-window (halves S,
//               softmax and PV work vs block-wide 112), exact full-row softmax
//               w/ masked-logit (=1e-9) fold, P fp16 -> PV MFMA vs LDS V^T
//   gemm_proj:  64x128 tiles, BK=128 four-plane (8 iters x 32 MFMA)
// ---------------------------------------------------------------------------

typedef _Float16 f16x8 __attribute__((ext_vector_type(8)));
typedef float    f32x4 __attribute__((ext_vector_type(4)));

#define MFMA16(a, b, c) __builtin_amdgcn_mfma_f32_16x16x32_f16((a), (b), (c), 0, 0, 0)

__device__ __forceinline__ void gl_lds16(const void* g, void* l) {
    __builtin_amdgcn_global_load_lds(
        (const __attribute__((address_space(1))) void*)g,
        (__attribute__((address_space(3))) void*)l, 16, 0, 0);
}

__device__ __forceinline__ ushort f2h(float f) {
    _Float16 h = (_Float16)f;
    return *(ushort*)&h;
}

// ---------------------------------------------------------------------------
// fused fp32 -> fp16 conversion for all three tensors + sall zeroing.
// ---------------------------------------------------------------------------
__global__ void split_all(const float* __restrict__ x,
                          const float* __restrict__ qkvw,
                          const float* __restrict__ projw,
                          ushort* __restrict__ x16,
                          ushort* __restrict__ w16,
                          ushort* __restrict__ pw16,
                          float* __restrict__ sall)
{
    const int i = blockIdx.x * 256 + threadIdx.x;
    if (i < 512) ((float4*)sall)[i] = make_float4(0.f, 0.f, 0.f, 0.f);
    const float* src; ushort* dst; int j;
    if (i < 1048576)      { src = x;     dst = x16;  j = i; }
    else if (i < 1835008) { src = qkvw;  dst = w16;  j = i - 1048576; }
    else                  { src = projw; dst = pw16; j = i - 1835008; }

    float4 v = ((const float4*)src)[j];
    ((ushort4*)dst)[j] = make_ushort4(f2h(v.x), f2h(v.y), f2h(v.z), f2h(v.w));
}

// ---------------------------------------------------------------------------
// qkv MFMA GEMM: 128x128 tile, BK=64 two-plane (32 KB). 16 iters x 32 MFMA.
// Scatter fp16 into q|k|v [3][B,H,N,64]. v-blocks (n0>=2048) also reduce
// their 64-row column partials and atomicAdd into sall[32][64] (fp32).
// ---------------------------------------------------------------------------
__global__ __launch_bounds__(256, 3) void gemm_mfma(
    const ushort* __restrict__ A_g, const ushort* __restrict__ W_g,
    ushort* __restrict__ out16, float* __restrict__ sall, int K)
{
    __shared__ ushort smem[16384];
    ushort* AS0 = smem;
    ushort* AS1 = smem + 4096;
    ushort* WS0 = smem + 8192;
    ushort* WS1 = smem + 12288;

    const int tid  = threadIdx.x;
    const int wid  = tid >> 6;
    const int lane = tid & 63;
    const int quad = lane >> 4;
    const int cl   = lane & 15;
    const int m0 = blockIdx.y * 128;
    const int n0 = blockIdx.x * 128;
    const int wm = (wid & 1) * 64;
    const int wn = (wid >> 1) * 64;

    const int srow = lane >> 2;
    const int scol = (lane & 3) * 8;

    const ushort* src = (wid < 2) ? A_g : W_g;
    ushort* dst = smem + wid * 4096;
    const int r0 = (wid < 2) ? m0 : n0;
    const int cofs = (wid & 1) * 32;

    f32x4 acc[4][4];
#pragma unroll
    for (int i = 0; i < 4; ++i)
#pragma unroll
        for (int j = 0; j < 4; ++j) acc[i][j] = (f32x4){0.f, 0.f, 0.f, 0.f};

    for (int k0 = 0; k0 < K; k0 += 64) {
#pragma unroll
        for (int c = 0; c < 8; ++c)
            gl_lds16(src + (size_t)(r0 + c * 16 + srow) * K + k0 + cofs + scol,
                     dst + c * 512);
        __syncthreads();

        f16x8 a0[4], w0[4];
#pragma unroll
        for (int i = 0; i < 4; ++i) {
            a0[i] = ((const f16x8*)AS0)[(wm + i * 16 + cl) * 4 + quad];
            w0[i] = ((const f16x8*)WS0)[(wn + i * 16 + cl) * 4 + quad];
        }
#pragma unroll
        for (int mi = 0; mi < 4; ++mi)
#pragma unroll
            for (int ni = 0; ni < 4; ++ni)
                acc[mi][ni] = MFMA16(a0[mi], w0[ni], acc[mi][ni]);

        f16x8 a1[4], w1[4];
#pragma unroll
        for (int i = 0; i < 4; ++i) {
            a1[i] = ((const f16x8*)AS1)[(wm + i * 16 + cl) * 4 + quad];
            w1[i] = ((const f16x8*)WS1)[(wn + i * 16 + cl) * 4 + quad];
        }
#pragma unroll
        for (int mi = 0; mi < 4; ++mi)
#pragma unroll
            for (int ni = 0; ni < 4; ++ni)
                acc[mi][ni] = MFMA16(a1[mi], w1[ni], acc[mi][ni]);
        __syncthreads();
    }

#pragma unroll
    for (int mi = 0; mi < 4; ++mi)
#pragma unroll
        for (int r = 0; r < 4; ++r) {
            const int gm = m0 + wm + mi * 16 + quad * 4 + r;
            const int b  = gm >> 11;
            const int nn = gm & 2047;
#pragma unroll
            for (int ni = 0; ni < 4; ++ni) {
                const int gn = n0 + wn + ni * 16 + cl;
                const int s  = gn >> 10;          // 0:q 1:k 2:v
                const int h  = (gn >> 6) & 15;
                const int dh = gn & 63;
                out16[(size_t)s * 4194304u + (((size_t)b * 16 + h) * 2048 + nn) * 64 + dh]
                    = f2h(acc[mi][ni][r]);
            }
        }

    // v-blocks: S_all partials (wave covers 64 rows, uniform b and h)
    if (n0 >= 2048) {
        const int b = (m0 + wm) >> 11;
        const int h = ((n0 + wn) >> 6) & 15;
#pragma unroll
        for (int ni = 0; ni < 4; ++ni) {
            float ps = 0.f;
#pragma unroll
            for (int mi = 0; mi < 4; ++mi)
#pragma unroll
                for (int r = 0; r < 4; ++r) ps += acc[mi][ni][r];
            ps += __shfl_xor(ps, 16);
            ps += __shfl_xor(ps, 32);
            if (quad == 0)
                atomicAdd(&sall[(b * 16 + h) * 64 + ni * 16 + cl], ps);
        }
    }
}

// ---------------------------------------------------------------------------
// Proj GEMM, 64x128 tiles (512 blocks = 2/CU), BK=128 four-plane (48 KB LDS).
// ---------------------------------------------------------------------------
__global__ __launch_bounds__(256, 2) void gemm_proj(
    const ushort* __restrict__ A_g, const ushort* __restrict__ W_g,
    const float* __restrict__ bias, float* __restrict__ out)
{
    const int K = 1024, Nout = 1024;
    __shared__ ushort smem[24576];

    const int tid  = threadIdx.x;
    const int wid  = tid >> 6;
    const int lane = tid & 63;
    const int quad = lane >> 4;
    const int cl   = lane & 15;
    const int m0 = blockIdx.y * 64;
    const int n0 = blockIdx.x * 128;
    const int wm = (wid & 1) * 32;
    const int wn = (wid >> 1) * 64;

    const int srow = lane >> 2;
    const int scol = (lane & 3) * 8;

    f32x4 acc[2][4];
#pragma unroll
    for (int i = 0; i < 2; ++i)
#pragma unroll
        for (int j = 0; j < 4; ++j) acc[i][j] = (f32x4){0.f, 0.f, 0.f, 0.f};

    for (int k0 = 0; k0 < K; k0 += 128) {
#pragma unroll
        for (int c = 0; c < 12; ++c) {
            const int cid = wid * 12 + c;
            const ushort* s; ushort* d; int rr, pl;
            if (cid < 16) {
                pl = cid >> 2;
                const int ch = cid & 3;
                s = A_g; rr = m0 + ch * 16;
                d = smem + pl * 2048 + ch * 512;
            } else {
                const int wc = cid - 16;
                pl = wc >> 3;
                const int ch = wc & 7;
                s = W_g; rr = n0 + ch * 16;
                d = smem + 8192 + pl * 4096 + ch * 512;
            }
            gl_lds16(s + (size_t)(rr + srow) * K + k0 + pl * 32 + scol, d);
        }
        __syncthreads();

#pragma unroll
        for (int pl = 0; pl < 4; ++pl) {
            const ushort* ASp = smem + pl * 2048;
            const ushort* WSp = smem + 8192 + pl * 4096;
            f16x8 a[2], w[4];
#pragma unroll
            for (int i = 0; i < 2; ++i)
                a[i] = ((const f16x8*)ASp)[(wm + i * 16 + cl) * 4 + quad];
#pragma unroll
            for (int i = 0; i < 4; ++i)
                w[i] = ((const f16x8*)WSp)[(wn + i * 16 + cl) * 4 + quad];
#pragma unroll
            for (int mi = 0; mi < 2; ++mi)
#pragma unroll
                for (int ni = 0; ni < 4; ++ni)
                    acc[mi][ni] = MFMA16(a[mi], w[ni], acc[mi][ni]);
        }
        __syncthreads();
    }

    float bb[4];
#pragma unroll
    for (int ni = 0; ni < 4; ++ni) bb[ni] = bias[n0 + wn + ni * 16 + cl];
#pragma unroll
    for (int mi = 0; mi < 2; ++mi)
#pragma unroll
        for (int r = 0; r < 4; ++r) {
            const int gm = m0 + wm + mi * 16 + quad * 4 + r;
            float* rowp = out + (size_t)gm * Nout;
#pragma unroll
            for (int ni = 0; ni < 4; ++ni) {
                const int gn = n0 + wn + ni * 16 + cl;
                rowp[gn] = acc[mi][ni][r] + bb[ni];
            }
        }
}

// ---------------------------------------------------------------------------
// MFMA flash-band attention (fp16), per-wave 64-wide K-window.
// Block = one (b,h) x 64 q-rows, 4 waves x 16 rows. A wave's rows touch only
// 16+2w+1 <= 57 K-cols; sbase = floor(s_min/8)*8 covers them in 64 cols
// (55 <= 56 slack guarantees coverage; sbase <= 48 keeps reads inside VT).
// ---------------------------------------------------------------------------
__global__ __launch_bounds__(256) void attn_mfma(
    const ushort* __restrict__ qg, const ushort* __restrict__ kg,
    const ushort* __restrict__ vg,
    const float* __restrict__ sall,
    ushort* __restrict__ outp,
    const int* __restrict__ epoch_ptr)
{
    const int N = 2048;
    const int w = (epoch_ptr[0] < 15) ? 16 : 20;

    __shared__ ushort Pl[4][16][72];      // per-wave P~ tile (64 cols + pad)
    __shared__ ushort VT[64][136];        // transposed V band [dim][seq]

    const int tid  = threadIdx.x;
    const int wid  = tid >> 6;
    const int lane = tid & 63;
    const int quad = lane >> 4;
    const int cl   = lane & 15;

    const int bh = blockIdx.x >> 5;
    const int n0 = (blockIdx.x & 31) << 6;
    const int lo = max(0, n0 - w);
    const int wm = wid * 16;
    const int hi = min(N - 1, n0 + 63 + w);
    const int cnt = hi - lo + 1;        // 80..104

    // zero VT cols [64,136) only (cnt >= 80 guarantees cols <64 get filled)
    for (int t = tid; t < 64 * 36; t += 256) {
        const int row = t / 36;
        const int c2  = 64 + (t - row * 36) * 2;
        *(unsigned*)&VT[row][c2] = 0u;
    }
    __syncthreads();    // zero visible before scatter overwrites [64,cnt)

    // scatter V band (coalesced reads) into VT transposed
    for (int t = tid; t < 104 * 8; t += 256) {
        const int s  = t >> 3;
        const int db = (t & 7) * 8;
        if (s < cnt) {
            uint4 vv = *(const uint4*)(vg + (((size_t)bh * N) + lo + s) * 64 + db);
            VT[db + 0][s] = (ushort)(vv.x & 0xffff); VT[db + 1][s] = (ushort)(vv.x >> 16);
            VT[db + 2][s] = (ushort)(vv.y & 0xffff); VT[db + 3][s] = (ushort)(vv.y >> 16);
            VT[db + 4][s] = (ushort)(vv.z & 0xffff); VT[db + 5][s] = (ushort)(vv.z >> 16);
            VT[db + 6][s] = (ushort)(vv.w & 0xffff); VT[db + 7][s] = (ushort)(vv.w >> 16);
        }
    }

    // per-wave K window base (multiple of 8, in VT coordinates)
    const int jminw = max(0, n0 + wm - w);
    const int sbase = ((jminw - lo) >> 3) << 3;

    const ushort* qp = qg + ((size_t)bh * N + n0 + wm + cl) * 64;
    const f16x8 aq0 = *(const f16x8*)(qp + quad * 8);
    const f16x8 aq1 = *(const f16x8*)(qp + 32 + quad * 8);

    f32x4 sacc[4];
#pragma unroll
    for (int ni = 0; ni < 4; ++ni) {
        int krow = lo + sbase + ni * 16 + cl;
        krow = min(krow, N - 1);                 // clamped rows masked later
        const ushort* kp = kg + ((size_t)bh * N + krow) * 64;
        const f16x8 bk0 = *(const f16x8*)(kp + quad * 8);
        const f16x8 bk1 = *(const f16x8*)(kp + 32 + quad * 8);
        f32x4 s = (f32x4){0.f, 0.f, 0.f, 0.f};
        s = MFMA16(aq0, bk0, s);
        s = MFMA16(aq1, bk1, s);
        sacc[ni] = s;
    }

    float pm[4];
#pragma unroll
    for (int r = 0; r < 4; ++r) {
        const int n = n0 + wm + quad * 4 + r;
        const int jlo = max(0, n - w), jhi = min(N - 1, n + w);
        const int bc = jhi - jlo + 1;
        float mx = 1e-9f;
#pragma unroll
        for (int ni = 0; ni < 4; ++ni) {
            const int j = lo + sbase + ni * 16 + cl;
            const bool val = (j >= n - w) && (j <= n + w) && (j < N);
            const float sv = 4.0f * sacc[ni][r];
            if (val) mx = fmaxf(mx, sv);
        }
        mx = fmaxf(mx, __shfl_xor(mx, 1));
        mx = fmaxf(mx, __shfl_xor(mx, 2));
        mx = fmaxf(mx, __shfl_xor(mx, 4));
        mx = fmaxf(mx, __shfl_xor(mx, 8));
        const float em = __expf(1e-9f - mx);
        float e[4];
        float sum = 0.f;
#pragma unroll
        for (int ni = 0; ni < 4; ++ni) {
            const int j = lo + sbase + ni * 16 + cl;
            const bool val = (j >= n - w) && (j <= n + w) && (j < N);
            const float ev = val ? __expf(4.0f * sacc[ni][r] - mx) : 0.f;
            e[ni] = val ? (ev - em) : 0.f;
            sum += ev;
        }
        sum += __shfl_xor(sum, 1);
        sum += __shfl_xor(sum, 2);
        sum += __shfl_xor(sum, 4);
        sum += __shfl_xor(sum, 8);
        const float inv = 1.0f / ((float)(N - bc) * em + sum);
        pm[r] = em * inv;
#pragma unroll
        for (int ni = 0; ni < 4; ++ni)
            sacc[ni][r] = e[ni] * inv;           // P~ = (e - em)/denom
    }

    // P~ -> LDS fp16 (all 64 cols written; invalid cols are exactly 0)
#pragma unroll
    for (int ni = 0; ni < 4; ++ni)
#pragma unroll
        for (int r = 0; r < 4; ++r)
            Pl[wid][quad * 4 + r][ni * 16 + cl] = f2h(sacc[ni][r]);

    __syncthreads();   // VT scatter complete

    // PV: out(16 rows x 64 dims) = P~ (16x64) . Vband[sbase..sbase+63]
    const int b = bh >> 4, h = bh & 15;
#pragma unroll
    for (int dn = 0; dn < 4; ++dn) {
        f32x4 o = (f32x4){0.f, 0.f, 0.f, 0.f};
#pragma unroll
        for (int k0 = 0; k0 < 64; k0 += 32) {
            const f16x8 a  = *(const f16x8*)&Pl[wid][cl][k0 + quad * 8];
            const f16x8 bb = *(const f16x8*)&VT[dn * 16 + cl][sbase + k0 + quad * 8];
            o = MFMA16(a, bb, o);
        }
        const int d = dn * 16 + cl;
        const float sv = sall[bh * 64 + d];
#pragma unroll
        for (int r = 0; r < 4; ++r) {
            const int n = n0 + wm + quad * 4 + r;
            outp[((size_t)b * N + n) * 1024 + h * 64 + d] = f2h(o[r] + pm[r] * sv);
        }
    }
}

extern "C" void kernel_launch(void* const* d_in, const int* in_sizes, int n_in,
                              void* d_out, int out_size, void* d_ws, size_t ws_size,
                              hipStream_t stream)
{
    const float* x      = (const float*)d_in[0];
    const float* qkv_w  = (const float*)d_in[1];
    const float* proj_w = (const float*)d_in[2];
    const float* proj_b = (const float*)d_in[3];
    const int*   epoch  = (const int*)d_in[4];
    float* out = (float*)d_out;

    const size_t BHND = (size_t)2 * 16 * 2048 * 64;   // 4,194,304
    const size_t XN = 4194304, WN = 3145728;

    ushort* qkv16 = (ushort*)d_ws;            // q|k|v fp16, contiguous
    ushort* q16   = qkv16;
    ushort* k16   = qkv16 + BHND;
    ushort* v16   = qkv16 + 2 * BHND;
    float*  sall  = (float*)(qkv16 + 3 * BHND);   // 2048 floats (pad 4096)
    ushort* x16   = (ushort*)(sall + 4096);
    ushort* w16   = x16 + XN;
    ushort* pw16  = w16 + WN;
    ushort* ao    = x16;   // alias: x16 dead after qkv gemm

    split_all<<<dim3(8192), dim3(256), 0, stream>>>(
        x, qkv_w, proj_w, x16, w16, pw16, sall);

    gemm_mfma<<<dim3(24, 32), dim3(256), 0, stream>>>(x16, w16, qkv16, sall, 1024);

    attn_mfma<<<dim3(1024), dim3(256), 0, stream>>>(q16, k16, v16, sall, ao, epoch);

    gemm_proj<<<dim3(8, 64), dim3(256), 0, stream>>>(ao, pw16, proj_b, out);
}